// Round 10
// baseline (946.992 us; speedup 1.0000x reference)
//
#include <hip/hip_runtime.h>
#include <hip/hip_bf16.h>

// ---------------------------------------------------------------------------
// VGG16 perceptual+style inpainting loss.
// v10 = v8 (769us, best) with conv kernels TEMPLATED ON CIN so the cb loop
// fully unrolls (trip 1/2/4). v9's manual pointer-array hoisting spilled to
// scratch (FETCH+WRITE +226MB/dispatch, VGPR pinned at 84 -> localMem);
// full unroll exposes the cb-invariant addressing to CSE as scalar SSA
// values instead -- compiler hoists into registers, no arrays.
// Everything else identical to v8: dispatch consolidation (merged L2 z=3NB,
// merged P1 transpose, merged perc/gram via gN/gtm, L7 outF=nullptr),
// v6 conv structure (4-row blocks, 3 blk/CU, MX-scaled fp8 MFMA scale=1.0,
// gld16 A-stage w/ inverse-swizzled source + zero-page halo, LDS-bounce
// dwordx4 epilogues). Workspace layout identical to v8.
// ---------------------------------------------------------------------------

typedef __attribute__((ext_vector_type(8))) short bf16x8_t;
typedef __attribute__((ext_vector_type(4))) float f32x4_t;
typedef __attribute__((ext_vector_type(16))) float f32x16_t;
typedef __attribute__((ext_vector_type(8))) int i32x8_t;

typedef const __attribute__((address_space(1))) void* gas_t;
typedef __attribute__((address_space(3))) void* las_t;

__device__ __forceinline__ void gld16(const void* g, void* l) {
  __builtin_amdgcn_global_load_lds((gas_t)g, (las_t)l, 16, 0, 0);
}

__device__ __forceinline__ unsigned char f2fp8(float v) {
  return (unsigned char)(__builtin_amdgcn_cvt_pk_fp8_f32(v, v, 0, false) & 0xff);
}

// Read one 32B fragment (logical chunks 2h,2h+1 of a 64B row) from a
// chunk-swizzled LDS tile. Swizzle: physical chunk = logical ^ ((row>>1)&3).
__device__ __forceinline__ i32x8_t ld_frag(const unsigned char* lds, int row,
                                           int h) {
  const int sw = (row >> 1) & 3;
  const unsigned char* base = lds + row * 64;
  uint4 lo = *(const uint4*)(base + (((2 * h) ^ sw) << 4));
  uint4 hi = *(const uint4*)(base + (((2 * h + 1) ^ sw) << 4));
  i32x8_t r;
  r[0] = lo.x; r[1] = lo.y; r[2] = lo.z; r[3] = lo.w;
  r[4] = hi.x; r[5] = hi.y; r[6] = hi.z; r[7] = hi.w;
  return r;
}

// 32 contiguous bytes global -> i32x8 (B fragment direct from L1/L2).
__device__ __forceinline__ i32x8_t ld32g(const unsigned char* p) {
  uint4 lo = *(const uint4*)p;
  uint4 hi = *(const uint4*)(p + 16);
  i32x8_t r;
  r[0] = lo.x; r[1] = lo.y; r[2] = lo.z; r[3] = lo.w;
  r[4] = hi.x; r[5] = hi.y; r[6] = hi.z; r[7] = hi.w;
  return r;
}

__device__ __forceinline__ float blk_sum256(float v, float* s4) {
#pragma unroll
  for (int o = 32; o > 0; o >>= 1) v += __shfl_down(v, o);
  int w = threadIdx.x >> 6;
  if ((threadIdx.x & 63) == 0) s4[w] = v;
  __syncthreads();
  float r = s4[0] + s4[1] + s4[2] + s4[3];
  __syncthreads();
  return r;
}

__global__ void init_slots(float* slots) {
  if (threadIdx.x < 32) slots[threadIdx.x] = 0.0f;  // slots[0..7] + zero-page
}

__global__ __launch_bounds__(256) void l1_kernel(
    const float* __restrict__ igt, const float* __restrict__ iout,
    const float* __restrict__ mask, float* __restrict__ slots) {
  __shared__ float s4[4];
  float ah = 0.0f, av = 0.0f;
  for (int idx = blockIdx.x * 256 + threadIdx.x; idx < 1572864;
       idx += gridDim.x * 256) {
    int pix = idx & 262143;
    int n = idx / 786432;
    float mk = mask[n * 262144 + pix];
    bool m = (mk != 0.0f);
    float d = fabsf(iout[idx] - igt[idx]);
    if (m) av += d; else ah += d;
  }
  float r = blk_sum256(ah, s4);
  if (threadIdx.x == 0) atomicAdd(&slots[0], r);
  r = blk_sum256(av, s4);
  if (threadIdx.x == 0) atomicAdd(&slots[1], r);
}

// Pack fp32 OIHW weights -> fp8 [tap][cout][cin] (plain). Dword stores.
__global__ __launch_bounds__(256) void pack_w(const float* __restrict__ w,
                                              unsigned char* __restrict__ wp,
                                              int Cin, int Cout) {
  int i = blockIdx.x * 256 + threadIdx.x;
  int c4n = Cin >> 2;
  if (i >= Cout * c4n * 9) return;
  int o = i % 9;
  int rem = i / 9;
  int c4 = rem % c4n;
  int co = rem / c4n;
  int dy = o / 3, dx = o % 3;
  unsigned r = 0;
#pragma unroll
  for (int k = 0; k < 4; ++k) {
    int ci = c4 * 4 + k;
    float v = w[((co * Cin + ci) * 3 + dy) * 3 + dx];
    r |= (unsigned)f2fp8(v) << (8 * k);
  }
  *(unsigned*)(wp + ((long)(o * Cout + co)) * Cin + c4 * 4) = r;
}

// Pack conv1 weights [64][3][3][3] OIHW -> bf16 [co][32], k=dy*9+dx*3+ci.
__global__ __launch_bounds__(256) void pack_w1(const float* __restrict__ w,
                                               __hip_bfloat16* __restrict__ wk) {
  int i = blockIdx.x * 256 + threadIdx.x;
  if (i >= 64 * 32) return;
  int co = i >> 5, k = i & 31;
  float v = 0.0f;
  if (k < 27) {
    int dy = k / 9, r = k - dy * 9;
    int dx = r / 3, ci = r - dx * 3;
    v = w[((co * 3 + ci) * 3 + dy) * 3 + dx];
  }
  wk[i] = __float2bfloat16(v);
}

// Build im2col-K32 bf16 input Apk[nl][y][x][32] for stream sid. (r10-proven)
__global__ __launch_bounds__(256) void pack2_kernel(
    const float* __restrict__ igt, const float* __restrict__ iout,
    const float* __restrict__ mask, __hip_bfloat16* __restrict__ apk, int sid,
    int n0, int NB) {
  int idx = blockIdx.x * 256 + threadIdx.x;
  if (idx >= NB * 262144) return;
  int nl = idx >> 18;
  int pix = idx & 262143;
  int y = pix >> 9, x = pix & 511;
  int sample = n0 + nl;
  __align__(16) __hip_bfloat16 buf[32];
#pragma unroll
  for (int k = 27; k < 32; ++k) buf[k] = __float2bfloat16(0.0f);
  for (int dy = 0; dy < 3; ++dy)
    for (int dx = 0; dx < 3; ++dx) {
      int gy = y - 1 + dy, gx = x - 1 + dx;
      bool inb = (gy >= 0 && gy < 512 && gx >= 0 && gx < 512);
      int p = gy * 512 + gx;
      bool useG;
      if (sid == 0) useG = true;
      else if (sid == 1) useG = false;
      else useG = inb && (mask[sample * 262144 + (inb ? p : 0)] != 0.0f);
      const float* src = useG ? igt : iout;
#pragma unroll
      for (int ci = 0; ci < 3; ++ci) {
        float v = inb ? src[sample * 786432 + ci * 262144 + p] : 0.0f;
        buf[dy * 9 + dx * 3 + ci] = __float2bfloat16(v);
      }
    }
  __hip_bfloat16* dst = apk + (long)idx * 32;
#pragma unroll
  for (int q = 0; q < 4; ++q)
    *(uint4*)&dst[q * 8] = *(const uint4*)&buf[q * 8];
}

// conv1: K=32 bf16 MFMA GEMM -> fp8 NHWC Y1. LDS bounce epilogue.
__global__ __launch_bounds__(256, 2) void conv1m(
    const __hip_bfloat16* __restrict__ apk, const __hip_bfloat16* __restrict__ wk,
    const float* __restrict__ bias, unsigned char* __restrict__ out) {
  __shared__ __align__(16) short ApS[512 * 32];
  __shared__ __align__(16) short BwS[64 * 32];
  const int tid = threadIdx.x;
  const int lane = tid & 63;
  const int wv = tid >> 6;
  const int quad = lane >> 4, l15 = lane & 15;
  const int n = blockIdx.z;
  const int x0 = blockIdx.x << 6;
  const int y0 = blockIdx.y << 3;
  const int spos = lane >> 2;  // entry within slab
  const int sq = lane & 3;     // 16B chunk within entry

  for (int u = wv; u < 32; u += 4) {
    int pos = (u << 4) + spos;
    int r = pos >> 6, c = pos & 63;
    gld16(apk + (((long)n * 512 + y0 + r) * 512 + x0 + c) * 32 + sq * 8,
          &ApS[u << 9]);
  }
  if (wv < 4) gld16(wk + spos * 32 + sq * 8, &BwS[wv << 9]);
  __syncthreads();

  f32x4_t acc[8][4];
#pragma unroll
  for (int mt = 0; mt < 8; ++mt)
#pragma unroll
    for (int nt = 0; nt < 4; ++nt) acc[mt][nt] = (f32x4_t)0.0f;

  bf16x8_t bf[4];
#pragma unroll
  for (int nt = 0; nt < 4; ++nt)
    bf[nt] = *(const bf16x8_t*)&BwS[(nt * 16 + l15) * 32 + quad * 8];
#pragma unroll
  for (int mt = 0; mt < 8; ++mt) {
    const int rl = 2 * wv + (mt >> 2);
    const int pl = (mt & 3) * 16 + l15;
    const bf16x8_t a = *(const bf16x8_t*)&ApS[(rl * 64 + pl) * 32 + quad * 8];
#pragma unroll
    for (int nt = 0; nt < 4; ++nt)
      acc[mt][nt] = __builtin_amdgcn_mfma_f32_16x16x32_bf16(a, bf[nt],
                                                            acc[mt][nt], 0, 0, 0);
  }

  float bv[4];
#pragma unroll
  for (int nt = 0; nt < 4; ++nt) bv[nt] = bias[nt * 16 + l15];

  __syncthreads();
  unsigned char* O8 = (unsigned char*)ApS;
#pragma unroll
  for (int mt = 0; mt < 8; ++mt) {
    const int ry = 2 * wv + (mt >> 2);
#pragma unroll
    for (int nt = 0; nt < 4; ++nt) {
      const int col = nt * 16 + l15;
#pragma unroll
      for (int reg = 0; reg < 4; ++reg) {
        int px = (mt & 3) * 16 + quad * 4 + reg;
        float v = fmaxf(acc[mt][nt][reg] + bv[nt], 0.0f);
        O8[((ry << 6) + px) * 64 + col] = f2fp8(v);
      }
    }
  }
  __syncthreads();
#pragma unroll
  for (int j = 0; j < 8; ++j) {
    int L = (j * 256 + tid) << 4;
    int x = (L >> 6) & 63;
    int cq = L & 63;
    *(uint4*)(out + (((long)n * 512 + y0 + j) * 512 + x0 + x) * 64 + cq) =
        *(const uint4*)&O8[L];
  }
}

// ---------------------------------------------------------------------------
// conv_f8 v10: v6/v8 body, CIN templated -> cb loop fully unrolled so the
// compiler CSEs cb-invariant addressing into registers (no arrays).
// 4-row block, wave = (row-pair pr, co-half ch), acc 64 regs, 3 blocks/CU.
// ---------------------------------------------------------------------------
template <int CIN>
__global__ __launch_bounds__(256, 3) void conv_f8(
    const unsigned char* __restrict__ act, const unsigned char* __restrict__ wp,
    const float* __restrict__ bias, unsigned char* __restrict__ out,
    const unsigned char* __restrict__ zp, int Cout, int H, int W) {
  __shared__ __align__(16) unsigned char ApS[400 * 64];
  const int tid = threadIdx.x;
  const int lane = tid & 63;
  const int wv = tid >> 6;
  const int l31 = lane & 31;
  const int h = lane >> 5;
  const int pr = wv & 1;   // row pair: rows 2pr, 2pr+1
  const int ch = wv >> 1;  // co half: ch*32
  const int coB = Cout >> 6;
  const int n = blockIdx.z / coB;
  const int co0 = (blockIdx.z % coB) << 6;
  const int x0 = blockIdx.x << 6;
  const int y0 = blockIdx.y << 2;
  const int spos = lane >> 2;
  const int sc = lane & 3;

  f32x16_t acc[2][2];
#pragma unroll
  for (int dr = 0; dr < 2; ++dr)
#pragma unroll
    for (int mh = 0; mh < 2; ++mh) acc[dr][mh] = (f32x16_t)0.0f;

#pragma unroll
  for (int cbi = 0; cbi < CIN / 64; ++cbi) {
    const int cb = cbi * 64;
    if (cbi) __syncthreads();  // guard ApS reuse
    for (int u = wv; u < 25; u += 4) {
      int pos = (u << 4) + spos;
      int q = sc ^ ((pos >> 1) & 3);  // inverse swizzle on the SOURCE
      int r = pos / 66, c = pos - r * 66;
      int gy = y0 - 1 + r, gx = x0 - 1 + c;
      const unsigned char* src = zp;
      if (pos < 396 && gy >= 0 && gy < H && gx >= 0 && gx < W)
        src = act + ((long)((long)n * H + gy) * W + gx) * CIN + cb + (q << 4);
      gld16(src, &ApS[u << 10]);
    }
    __syncthreads();

    const unsigned char* wl =
        wp + ((long)(co0 + (ch << 5) + l31)) * CIN + cb + (h << 5);
#pragma unroll
    for (int dx = 0; dx < 3; ++dx) {
      i32x8_t Af[2][4];
#pragma unroll
      for (int mh = 0; mh < 2; ++mh)
#pragma unroll
        for (int ri = 0; ri < 4; ++ri)
          Af[mh][ri] =
              ld_frag(ApS, (2 * pr + ri) * 66 + mh * 32 + l31 + dx, h);
#pragma unroll
      for (int dy = 0; dy < 3; ++dy) {
        const int o = dy * 3 + dx;
        i32x8_t Bf = ld32g(wl + (long)o * Cout * CIN);
#pragma unroll
        for (int dr = 0; dr < 2; ++dr)
#pragma unroll
          for (int mh = 0; mh < 2; ++mh)
            acc[dr][mh] = __builtin_amdgcn_mfma_scale_f32_32x32x64_f8f6f4(
                Af[mh][dr + dy], Bf, acc[dr][mh], 0, 0, 0,
                0x7F7F7F7F, 0, 0x7F7F7F7F);
      }
    }
  }

  const float bv = bias[co0 + (ch << 5) + l31];

  // LDS bounce: ApS reused as fp8 tile [ry 4][x 64][co 64] = 16KB.
  __syncthreads();
#pragma unroll
  for (int dr = 0; dr < 2; ++dr) {
    const int ry = 2 * pr + dr;
#pragma unroll
    for (int mh = 0; mh < 2; ++mh) {
#pragma unroll
      for (int reg = 0; reg < 16; ++reg) {
        int rowM = (reg & 3) + 8 * (reg >> 2) + 4 * h;
        int x = mh * 32 + rowM;
        float v = fmaxf(acc[dr][mh][reg] + bv, 0.0f);
        ApS[((ry << 6) + x) * 64 + (ch << 5) + l31] = f2fp8(v);
      }
    }
  }
  __syncthreads();
#pragma unroll
  for (int j = 0; j < 4; ++j) {
    int L = (j * 256 + tid) << 4;
    int ry = L >> 12;
    int x = (L >> 6) & 63;
    int cq = L & 63;
    *(uint4*)(out + (((long)n * H + y0 + ry) * W + x0 + x) * Cout + co0 + cq) =
        *(const uint4*)&ApS[L];
  }
}

// conv_f8p v10: conv_f8 + fused 2x2 maxpool; wide dual-store via LDS bounce.
// outF may be nullptr (fp8 output unused, e.g. last layer).
template <int CIN>
__global__ __launch_bounds__(256, 3) void conv_f8p(
    const unsigned char* __restrict__ act, const unsigned char* __restrict__ wp,
    const float* __restrict__ bias, unsigned char* __restrict__ outF,
    __hip_bfloat16* __restrict__ outB, const unsigned char* __restrict__ zp,
    int Cout, int H, int W) {
  __shared__ __align__(16) unsigned char ApS[400 * 64];
  const int tid = threadIdx.x;
  const int lane = tid & 63;
  const int wv = tid >> 6;
  const int l31 = lane & 31;
  const int h = lane >> 5;
  const int pr = wv & 1;
  const int ch = wv >> 1;
  const int coB = Cout >> 6;
  const int n = blockIdx.z / coB;
  const int co0 = (blockIdx.z % coB) << 6;
  const int x0g = blockIdx.x << 6;
  const int y0 = blockIdx.y << 2;
  const int spos = lane >> 2;
  const int sc = lane & 3;

  f32x16_t acc[2][2];
#pragma unroll
  for (int dr = 0; dr < 2; ++dr)
#pragma unroll
    for (int mh = 0; mh < 2; ++mh) acc[dr][mh] = (f32x16_t)0.0f;

#pragma unroll
  for (int cbi = 0; cbi < CIN / 64; ++cbi) {
    const int cb = cbi * 64;
    if (cbi) __syncthreads();
    for (int u = wv; u < 25; u += 4) {
      int pos = (u << 4) + spos;
      int q = sc ^ ((pos >> 1) & 3);
      int r = pos / 66, c = pos - r * 66;
      int gy = y0 - 1 + r, gx = x0g - 1 + c;
      const unsigned char* src = zp;
      if (pos < 396 && gy >= 0 && gy < H && gx >= 0 && gx < W)
        src = act + ((long)((long)n * H + gy) * W + gx) * CIN + cb + (q << 4);
      gld16(src, &ApS[u << 10]);
    }
    __syncthreads();

    const unsigned char* wl =
        wp + ((long)(co0 + (ch << 5) + l31)) * CIN + cb + (h << 5);
#pragma unroll
    for (int dx = 0; dx < 3; ++dx) {
      i32x8_t Af[2][4];
#pragma unroll
      for (int mh = 0; mh < 2; ++mh)
#pragma unroll
        for (int ri = 0; ri < 4; ++ri)
          Af[mh][ri] =
              ld_frag(ApS, (2 * pr + ri) * 66 + mh * 32 + l31 + dx, h);
#pragma unroll
      for (int dy = 0; dy < 3; ++dy) {
        const int o = dy * 3 + dx;
        i32x8_t Bf = ld32g(wl + (long)o * Cout * CIN);
#pragma unroll
        for (int dr = 0; dr < 2; ++dr)
#pragma unroll
          for (int mh = 0; mh < 2; ++mh)
            acc[dr][mh] = __builtin_amdgcn_mfma_scale_f32_32x32x64_f8f6f4(
                Af[mh][dr + dy], Bf, acc[dr][mh], 0, 0, 0,
                0x7F7F7F7F, 0, 0x7F7F7F7F);
      }
    }
  }

  const int Ho = H >> 1, Wo = W >> 1;
  const int ho0 = blockIdx.y << 1;
  const int wo0 = blockIdx.x << 5;
  const float bv = bias[co0 + (ch << 5) + l31];

  // LDS bounce: fp8 tile [ho 2][wo 32][co 64] = 4KB, bf16 same layout 8KB.
  __syncthreads();
  unsigned char* F8 = ApS;
  __hip_bfloat16* BB = (__hip_bfloat16*)(ApS + 4096);
#pragma unroll
  for (int mh = 0; mh < 2; ++mh) {
#pragma unroll
    for (int p8 = 0; p8 < 8; ++p8) {
      const int reg = 2 * p8;  // (reg,reg+1) = x-adjacent pair
      float m0 = fmaxf(fmaxf(acc[0][mh][reg], acc[0][mh][reg + 1]),
                       fmaxf(acc[1][mh][reg], acc[1][mh][reg + 1]));
      float v = fmaxf(m0 + bv, 0.0f);
      int rowM = (reg & 3) + 8 * (reg >> 2) + 4 * h;
      int wo = mh * 16 + (rowM >> 1);  // 0..31
      int off = ((pr * 32 + wo) << 6) + (ch << 5) + l31;
      if (outF) F8[off] = f2fp8(v);
      BB[off] = __float2bfloat16(v);
    }
  }
  __syncthreads();
  if (outF) {
    int L = tid << 4;
    int hl = L >> 11;
    int wo = (L >> 6) & 31;
    int cq = L & 63;
    *(uint4*)(outF + (((long)n * Ho + ho0 + hl) * Wo + wo0 + wo) * Cout + co0 +
              cq) = *(const uint4*)&F8[L];
  }
#pragma unroll
  for (int j = 0; j < 2; ++j) {
    int S = (j * 256 + tid) << 3;  // short index
    int hl = S >> 11;
    int wo = (S >> 6) & 31;
    int cq = S & 63;
    *(uint4*)(outB + (((long)n * Ho + ho0 + hl) * Wo + wo0 + wo) * Cout + co0 +
              cq) = *(const uint4*)&BB[S];
  }
}

// NHWC [j][Ho][Wo][C] -> col-major planar [(j*C+c)][Wo][Ho]. (r10-proven)
__global__ __launch_bounds__(256) void transpose_k(
    const __hip_bfloat16* __restrict__ in, __hip_bfloat16* __restrict__ out,
    int C, int Ho, int Wo) {
  const int cl = threadIdx.x & 31;
  const int wl = threadIdx.x >> 5;
  const int cg = C >> 5;
  const int j = blockIdx.z / cg;
  const int c = (blockIdx.z % cg) * 32 + cl;
  const int wo = blockIdx.x * 8 + wl;
  const int ho0 = blockIdx.y * 8;
  __align__(16) __hip_bfloat16 res[8];
#pragma unroll
  for (int i = 0; i < 8; ++i)
    res[i] = in[(((long)j * Ho + ho0 + i) * Wo + wo) * C + c];
  *(uint4*)&out[((long)(j * C + c) * Wo + wo) * Ho + ho0] =
      *(const uint4*)res;
}

// l_perc partial: sum |cur - gt| over 8*M8 bf16 elements -> slots[2].
// gt repeats every gN 16B-groups (merged multi-stream compare).
__global__ __launch_bounds__(256) void perc_kernel(
    const __hip_bfloat16* __restrict__ gt, const __hip_bfloat16* __restrict__ cur,
    int M8, int gN, float* __restrict__ slots) {
  __shared__ float s4[4];
  const uint4* g4 = (const uint4*)gt;
  const uint4* c4 = (const uint4*)cur;
  float acc = 0.0f;
  for (int i = blockIdx.x * 256 + threadIdx.x; i < M8; i += gridDim.x * 256) {
    int ig = (i >= gN) ? i - gN : i;
    uint4 g = g4[ig], c = c4[i];
    const unsigned* gu = (const unsigned*)&g;
    const unsigned* cu = (const unsigned*)&c;
#pragma unroll
    for (int k = 0; k < 4; ++k) {
      float g0 = __uint_as_float(gu[k] << 16);
      float g1 = __uint_as_float(gu[k] & 0xffff0000u);
      float c0 = __uint_as_float(cu[k] << 16);
      float c1 = __uint_as_float(cu[k] & 0xffff0000u);
      acc += fabsf(c0 - g0) + fabsf(c1 - g1);
    }
  }
  float r = blk_sum256(acc, s4);
  if (threadIdx.x == 0) atomicAdd(&slots[2], r);
}

// Style partial via bf16 MFMA (r5-proven). Inputs col-major planar bf16.
// gt planes repeat every gtm z-planes (merged multi-stream compare).
template <int BM>
__global__ __launch_bounds__(256) void gram_mfma(
    const __hip_bfloat16* __restrict__ gt_p,
    const __hip_bfloat16* __restrict__ cur_p, int Wp, int Hp, int gtm,
    float fscale, float* __restrict__ slots) {
  constexpr int COLS = BM + 64;
  constexpr int WR = BM / 4;
  constexpr int MT = WR / 16;
  __shared__ __align__(16) short S[2 * COLS * 40];
  __shared__ float s4[4];
  const int tid = threadIdx.x;
  const int lane = tid & 63;
  const int wvi = tid >> 6;
  const int quad = lane >> 4, l15 = lane & 15;
  const int vt = blockIdx.x * 64;
  const int wt = blockIdx.y * BM;
  const long plane = (long)blockIdx.z * Wp * Hp;
  const long plane_g = (long)(blockIdx.z % gtm) * Wp * Hp;
  const __hip_bfloat16* bases[2] = {gt_p + plane_g, cur_p + plane};

  f32x4_t acc[2][MT][4];
#pragma unroll
  for (int t = 0; t < 2; ++t)
#pragma unroll
    for (int mt = 0; mt < MT; ++mt)
#pragma unroll
      for (int nt = 0; nt < 4; ++nt) acc[t][mt][nt] = (f32x4_t)0.0f;

  const int nchunk = 2 * COLS * 4;
  for (int h0 = 0; h0 < Hp; h0 += 32) {
    for (int e = tid; e < nchunk; e += 256) {
      int chunk = e & 3;
      int colt = e >> 2;
      int t = colt / COLS;
      int col = colt - t * COLS;
      int sc = (col < BM) ? (wt + col) : (vt + col - BM);
      uint4 v = *(const uint4*)(bases[t] + (long)sc * Hp + h0 + chunk * 8);
      *(uint4*)&S[(t * COLS + col) * 40 + chunk * 8] = v;
    }
    __syncthreads();
#pragma unroll
    for (int t = 0; t < 2; ++t) {
      bf16x8_t bf[4];
#pragma unroll
      for (int nt = 0; nt < 4; ++nt)
        bf[nt] = *(const bf16x8_t*)&S[(t * COLS + BM + nt * 16 + l15) * 40 +
                                      quad * 8];
#pragma unroll
      for (int mt = 0; mt < MT; ++mt) {
        bf16x8_t a = *(const bf16x8_t*)&S[(t * COLS + wvi * WR + mt * 16 + l15) *
                                              40 + quad * 8];
#pragma unroll
        for (int nt = 0; nt < 4; ++nt)
          acc[t][mt][nt] = __builtin_amdgcn_mfma_f32_16x16x32_bf16(
              a, bf[nt], acc[t][mt][nt], 0, 0, 0);
      }
    }
    __syncthreads();
  }

  float local = 0.0f;
#pragma unroll
  for (int mt = 0; mt < MT; ++mt)
#pragma unroll
    for (int nt = 0; nt < 4; ++nt)
#pragma unroll
      for (int reg = 0; reg < 4; ++reg)
        local += fabsf(acc[1][mt][nt][reg] - acc[0][mt][nt][reg]);
  float r = blk_sum256(local, s4);
  if (tid == 0) atomicAdd(&slots[3], r * fscale);
}

__global__ void combine_kernel(const float* __restrict__ slots,
                               float* __restrict__ out) {
  if (threadIdx.x == 0) {
    const float Nn = 1572864.0f;
    const float Nigt = 8388608.0f;
    out[0] = 2.0f * slots[0] / Nn + slots[1] / Nn + slots[2] / Nigt + slots[3];
  }
}

extern "C" void kernel_launch(void* const* d_in, const int* in_sizes, int n_in,
                              void* d_out, int out_size, void* d_ws,
                              size_t ws_size, hipStream_t stream) {
  (void)in_sizes; (void)n_in; (void)out_size;
  const float* igt = (const float*)d_in[0];
  const float* iout = (const float*)d_in[1];
  const float* mask = (const float*)d_in[2];
  const float* w[7];
  const float* b[7];
  for (int i = 0; i < 7; ++i) {
    w[i] = (const float*)d_in[3 + 2 * i];
    b[i] = (const float*)d_in[4 + 2 * i];
  }
  float* slots = (float*)d_ws;
  const unsigned char* zp = (const unsigned char*)d_ws + 64;  // 16B zeros

  unsigned char* wpk = (unsigned char*)((char*)d_ws + 256);
  const long wpOff[6] = {0, 36864, 110592, 258048, 552960, 1142784};
  const int wpCin[6] = {64, 64, 128, 128, 256, 256};
  const int wpCout[6] = {64, 128, 128, 256, 256, 256};
  __hip_bfloat16* w1k = (__hip_bfloat16*)((char*)d_ws + 256 + 1732608);
  // weights end at byte 1,736,960

  const size_t NEED2 = 194674944ULL;
  const int NB = (ws_size >= NEED2) ? 2 : 1;
  const int B3 = 3 * NB;
  const size_t M = (size_t)NB;  // scale factor

  char* base = (char*)d_ws + 1736960;
  // Region A (Apk region): M*16,777,216
  __hip_bfloat16* Apk = (__hip_bfloat16*)base;             // stage-1 im2col
  unsigned char* P1N8 = (unsigned char*)base;              // after conv1m done
  __hip_bfloat16* P2T = (__hip_bfloat16*)base;             // after L3 done
  // Region B (Y1 region): at M*16,777,216, size M*50,331,648
  char* Y1base = base + M * 16777216;
  unsigned char* Y1 = (unsigned char*)Y1base;              // Y1[3] contiguous
  __hip_bfloat16* pgT1 = (__hip_bfloat16*)Y1base;          // after L2 done
  __hip_bfloat16* pcT1 = (__hip_bfloat16*)(Y1base + M * 8388608);
  unsigned char* P2N8 = (unsigned char*)(Y1base + M * 25165824);
  __hip_bfloat16* P2Nb = (__hip_bfloat16*)(Y1base + M * 31457280);
  __hip_bfloat16* P3Nb = (__hip_bfloat16*)Y1base;          // after P1 gram done
  __hip_bfloat16* P3T = (__hip_bfloat16*)(Y1base + M * 6291456);
  // Region C (P1Nb region): at M*67,108,864, size M*25,165,824
  char* Cbase = base + M * 67108864;
  __hip_bfloat16* P1Nb = (__hip_bfloat16*)Cbase;           // 3 streams contig
  unsigned char* T = (unsigned char*)Cbase;                // after transpose P1
  unsigned char* Y5 = (unsigned char*)Cbase;               // after L4 done
  unsigned char* Y6 = (unsigned char*)(Cbase + M * 12582912);
  // End of workspace use: base + M*92,274,688 = 186,286,336 bytes < NEED2.

  const float fs1 = (float)(1.0 / (4194304.0 * 4096.0));
  const float fs2 = (float)(1.0 / (2097152.0 * 16384.0));
  const float fs3 = (float)(1.0 / (1048576.0 * 65536.0));

  init_slots<<<1, 64, 0, stream>>>(slots);
  l1_kernel<<<304, 256, 0, stream>>>(igt, iout, mask, slots);
  for (int l = 0; l < 6; ++l) {
    int elems = wpCout[l] * (wpCin[l] >> 2) * 9;
    pack_w<<<(elems + 255) / 256, 256, 0, stream>>>(w[l + 1], wpk + wpOff[l],
                                                    wpCin[l], wpCout[l]);
  }
  pack_w1<<<8, 256, 0, stream>>>(w[0], w1k);

  for (int n0 = 0; n0 < 2; n0 += NB) {
    // Stage 1: all 3 streams through conv1 first (Y1[3] contiguous) ...
    for (int s = 0; s < 3; ++s) {
      pack2_kernel<<<NB * 1024, 256, 0, stream>>>(igt, iout, mask, Apk, s, n0,
                                                  NB);
      conv1m<<<dim3(8, 64, NB), 256, 0, stream>>>(
          Apk, w1k, b[0], Y1 + (size_t)s * M * 16777216);
    }
    // ... then ONE merged L2 conv+pool over 3*NB images.
    conv_f8p<64><<<dim3(8, 128, 3 * NB), 256, 0, stream>>>(
        Y1, wpk + wpOff[0], b[1], P1N8, P1Nb, zp, 64, 512, 512);
    // ONE merged transpose: P1Nb[3*NB] -> pgT1|pcT1 (contiguous planes).
    transpose_k<<<dim3(32, 32, 3 * NB * 2), 256, 0, stream>>>(P1Nb, pgT1, 64,
                                                              256, 256);
    // Merged perc+gram over both compare pairs (gt repeats via gN/gtm).
    perc_kernel<<<304, 256, 0, stream>>>(pgT1, pcT1, NB * 1048576,
                                         NB * 524288, slots);
    gram_mfma<128><<<dim3(4, 2, NB * 128), 256, 0, stream>>>(
        pgT1, pcT1, 256, 256, NB * 64, fs1, slots);

    // Stage 2.
    conv_f8<64><<<dim3(4, 64, B3 * 2), 256, 0, stream>>>(
        P1N8, wpk + wpOff[1], b[2], T, zp, 128, 256, 256);
    conv_f8p<128><<<dim3(4, 64, B3 * 2), 256, 0, stream>>>(
        T, wpk + wpOff[2], b[3], P2N8, P2Nb, zp, 128, 256, 256);
    transpose_k<<<dim3(16, 16, B3 * 4), 256, 0, stream>>>(P2Nb, P2T, 128, 128,
                                                          128);
    perc_kernel<<<304, 256, 0, stream>>>(P2T, P2T + M * 2097152, NB * 524288,
                                         NB * 262144, slots);
    gram_mfma<128><<<dim3(2, 1, NB * 256), 256, 0, stream>>>(
        P2T, P2T + M * 2097152, 128, 128, NB * 128, fs2, slots);

    // Stage 3.
    conv_f8<128><<<dim3(2, 32, B3 * 4), 256, 0, stream>>>(
        P2N8, wpk + wpOff[3], b[4], Y5, zp, 256, 128, 128);
    conv_f8<256><<<dim3(2, 32, B3 * 4), 256, 0, stream>>>(
        Y5, wpk + wpOff[4], b[5], Y6, zp, 256, 128, 128);
    conv_f8p<256><<<dim3(2, 32, B3 * 4), 256, 0, stream>>>(
        Y6, wpk + wpOff[5], b[6], (unsigned char*)nullptr, P3Nb, zp, 256, 128,
        128);
    transpose_k<<<dim3(8, 8, B3 * 8), 256, 0, stream>>>(P3Nb, P3T, 256, 64, 64);
    perc_kernel<<<304, 256, 0, stream>>>(P3T, P3T + M * 1048576, NB * 262144,
                                         NB * 131072, slots);
    gram_mfma<64><<<dim3(1, 1, NB * 512), 256, 0, stream>>>(
        P3T, P3T + M * 1048576, 64, 64, NB * 256, fs3, slots);
  }

  combine_kernel<<<1, 64, 0, stream>>>(slots, (float*)d_out);
}

// Round 11
// 753.054 us; speedup vs baseline: 1.2575x; 1.2575x over previous
//
#include <hip/hip_runtime.h>
#include <hip/hip_bf16.h>

// ---------------------------------------------------------------------------
// VGG16 perceptual+style inpainting loss.
// v11 = v8 EXACT (769us, best measured) + prologue consolidation: the 8
// independent prologue dispatches (6x pack_w, pack_w1, l1_kernel) fold into
// ONE pack_all kernel via block-range dispatch (uniform scalar if-chains,
// no runtime-indexed arrays -> no scratch). v9/v10's VALU-hoisting attempts
// both spilled: at __launch_bounds__(256,3) the ~170-reg budget minus the
// 64-reg accumulator cannot hold the cb-invariant addressing; r8's 27%
// VALUBusy is the price of 3 blk/CU and stays.
// conv kernels verbatim v6/v8: 4-row blocks, 3 blk/CU, MX-scaled fp8 MFMA
// (scale=1.0), gld16 A-stage (inverse-swizzled source, zero-page halo),
// W global->reg, LDS-bounce dwordx4 epilogues. Dispatch consolidation:
// merged L2 (z=3NB), merged P1 transpose, merged perc/gram via gN/gtm,
// L7 outF=nullptr. Workspace layout identical to v8.
// ---------------------------------------------------------------------------

typedef __attribute__((ext_vector_type(8))) short bf16x8_t;
typedef __attribute__((ext_vector_type(4))) float f32x4_t;
typedef __attribute__((ext_vector_type(16))) float f32x16_t;
typedef __attribute__((ext_vector_type(8))) int i32x8_t;

typedef const __attribute__((address_space(1))) void* gas_t;
typedef __attribute__((address_space(3))) void* las_t;

__device__ __forceinline__ void gld16(const void* g, void* l) {
  __builtin_amdgcn_global_load_lds((gas_t)g, (las_t)l, 16, 0, 0);
}

__device__ __forceinline__ unsigned char f2fp8(float v) {
  return (unsigned char)(__builtin_amdgcn_cvt_pk_fp8_f32(v, v, 0, false) & 0xff);
}

// Read one 32B fragment (logical chunks 2h,2h+1 of a 64B row) from a
// chunk-swizzled LDS tile. Swizzle: physical chunk = logical ^ ((row>>1)&3).
__device__ __forceinline__ i32x8_t ld_frag(const unsigned char* lds, int row,
                                           int h) {
  const int sw = (row >> 1) & 3;
  const unsigned char* base = lds + row * 64;
  uint4 lo = *(const uint4*)(base + (((2 * h) ^ sw) << 4));
  uint4 hi = *(const uint4*)(base + (((2 * h + 1) ^ sw) << 4));
  i32x8_t r;
  r[0] = lo.x; r[1] = lo.y; r[2] = lo.z; r[3] = lo.w;
  r[4] = hi.x; r[5] = hi.y; r[6] = hi.z; r[7] = hi.w;
  return r;
}

// 32 contiguous bytes global -> i32x8 (B fragment direct from L1/L2).
__device__ __forceinline__ i32x8_t ld32g(const unsigned char* p) {
  uint4 lo = *(const uint4*)p;
  uint4 hi = *(const uint4*)(p + 16);
  i32x8_t r;
  r[0] = lo.x; r[1] = lo.y; r[2] = lo.z; r[3] = lo.w;
  r[4] = hi.x; r[5] = hi.y; r[6] = hi.z; r[7] = hi.w;
  return r;
}

__device__ __forceinline__ float blk_sum256(float v, float* s4) {
#pragma unroll
  for (int o = 32; o > 0; o >>= 1) v += __shfl_down(v, o);
  int w = threadIdx.x >> 6;
  if ((threadIdx.x & 63) == 0) s4[w] = v;
  __syncthreads();
  float r = s4[0] + s4[1] + s4[2] + s4[3];
  __syncthreads();
  return r;
}

__global__ void init_slots(float* slots) {
  if (threadIdx.x < 32) slots[threadIdx.x] = 0.0f;  // slots[0..7] + zero-page
}

// ---------------------------------------------------------------------------
// pack_all: merged prologue. Block ranges:
//  [0,1692)    pack_w for layers 0..5 (fp32 OIHW -> fp8 [tap][cout][cin])
//  [1692,1700) pack_w1 (conv1 weights -> bf16 [co][32])
//  [1700,2004) l1_kernel (hole/valid L1 partials -> slots[0..1])
// Per-layer block counts are exact multiples (36,72,144,288,576,576).
// ---------------------------------------------------------------------------
__global__ __launch_bounds__(256) void pack_all(
    const float* __restrict__ w1, const float* __restrict__ w2,
    const float* __restrict__ w3, const float* __restrict__ w4,
    const float* __restrict__ w5, const float* __restrict__ w6,
    const float* __restrict__ w7, const float* __restrict__ igt,
    const float* __restrict__ iout, const float* __restrict__ mask,
    unsigned char* __restrict__ wpk, __hip_bfloat16* __restrict__ w1k,
    float* __restrict__ slots) {
  __shared__ float s4[4];
  const int b = blockIdx.x;
  if (b < 1692) {
    // --- pack_w segment: uniform scalar layer select (no indexed arrays) ---
    int start, Cin, Cout;
    long off;
    const float* w;
    if (b < 36)        { start = 0;    Cin = 64;  Cout = 64;  off = 0;       w = w2; }
    else if (b < 108)  { start = 36;   Cin = 64;  Cout = 128; off = 36864;   w = w3; }
    else if (b < 252)  { start = 108;  Cin = 128; Cout = 128; off = 110592;  w = w4; }
    else if (b < 540)  { start = 252;  Cin = 128; Cout = 256; off = 258048;  w = w5; }
    else if (b < 1116) { start = 540;  Cin = 256; Cout = 256; off = 552960;  w = w6; }
    else               { start = 1116; Cin = 256; Cout = 256; off = 1142784; w = w7; }
    unsigned char* wp = wpk + off;
    int i = (b - start) * 256 + threadIdx.x;
    int c4n = Cin >> 2;
    int o = i % 9;
    int rem = i / 9;
    int c4 = rem % c4n;
    int co = rem / c4n;
    int dy = o / 3, dx = o % 3;
    unsigned r = 0;
#pragma unroll
    for (int k = 0; k < 4; ++k) {
      int ci = c4 * 4 + k;
      float v = w[((co * Cin + ci) * 3 + dy) * 3 + dx];
      r |= (unsigned)f2fp8(v) << (8 * k);
    }
    *(unsigned*)(wp + ((long)(o * Cout + co)) * Cin + c4 * 4) = r;
  } else if (b < 1700) {
    // --- pack_w1 segment ---
    int i = (b - 1692) * 256 + threadIdx.x;  // < 2048
    int co = i >> 5, k = i & 31;
    float v = 0.0f;
    if (k < 27) {
      int dy = k / 9, r = k - dy * 9;
      int dx = r / 3, ci = r - dx * 3;
      v = w1[((co * 3 + ci) * 3 + dy) * 3 + dx];
    }
    w1k[i] = __float2bfloat16(v);
  } else {
    // --- l1 segment: 304 virtual blocks, grid-stride 304*256 ---
    int vb = b - 1700;
    float ah = 0.0f, av = 0.0f;
    for (int idx = vb * 256 + threadIdx.x; idx < 1572864; idx += 304 * 256) {
      int pix = idx & 262143;
      int n = idx / 786432;
      float mk = mask[n * 262144 + pix];
      bool m = (mk != 0.0f);
      float d = fabsf(iout[idx] - igt[idx]);
      if (m) av += d; else ah += d;
    }
    float r = blk_sum256(ah, s4);
    if (threadIdx.x == 0) atomicAdd(&slots[0], r);
    r = blk_sum256(av, s4);
    if (threadIdx.x == 0) atomicAdd(&slots[1], r);
  }
}

// Build im2col-K32 bf16 input Apk[nl][y][x][32] for stream sid. (r10-proven)
__global__ __launch_bounds__(256) void pack2_kernel(
    const float* __restrict__ igt, const float* __restrict__ iout,
    const float* __restrict__ mask, __hip_bfloat16* __restrict__ apk, int sid,
    int n0, int NB) {
  int idx = blockIdx.x * 256 + threadIdx.x;
  if (idx >= NB * 262144) return;
  int nl = idx >> 18;
  int pix = idx & 262143;
  int y = pix >> 9, x = pix & 511;
  int sample = n0 + nl;
  __align__(16) __hip_bfloat16 buf[32];
#pragma unroll
  for (int k = 27; k < 32; ++k) buf[k] = __float2bfloat16(0.0f);
  for (int dy = 0; dy < 3; ++dy)
    for (int dx = 0; dx < 3; ++dx) {
      int gy = y - 1 + dy, gx = x - 1 + dx;
      bool inb = (gy >= 0 && gy < 512 && gx >= 0 && gx < 512);
      int p = gy * 512 + gx;
      bool useG;
      if (sid == 0) useG = true;
      else if (sid == 1) useG = false;
      else useG = inb && (mask[sample * 262144 + (inb ? p : 0)] != 0.0f);
      const float* src = useG ? igt : iout;
#pragma unroll
      for (int ci = 0; ci < 3; ++ci) {
        float v = inb ? src[sample * 786432 + ci * 262144 + p] : 0.0f;
        buf[dy * 9 + dx * 3 + ci] = __float2bfloat16(v);
      }
    }
  __hip_bfloat16* dst = apk + (long)idx * 32;
#pragma unroll
  for (int q = 0; q < 4; ++q)
    *(uint4*)&dst[q * 8] = *(const uint4*)&buf[q * 8];
}

// conv1: K=32 bf16 MFMA GEMM -> fp8 NHWC Y1. LDS bounce epilogue.
__global__ __launch_bounds__(256, 2) void conv1m(
    const __hip_bfloat16* __restrict__ apk, const __hip_bfloat16* __restrict__ wk,
    const float* __restrict__ bias, unsigned char* __restrict__ out) {
  __shared__ __align__(16) short ApS[512 * 32];
  __shared__ __align__(16) short BwS[64 * 32];
  const int tid = threadIdx.x;
  const int lane = tid & 63;
  const int wv = tid >> 6;
  const int quad = lane >> 4, l15 = lane & 15;
  const int n = blockIdx.z;
  const int x0 = blockIdx.x << 6;
  const int y0 = blockIdx.y << 3;
  const int spos = lane >> 2;  // entry within slab
  const int sq = lane & 3;     // 16B chunk within entry

  for (int u = wv; u < 32; u += 4) {
    int pos = (u << 4) + spos;
    int r = pos >> 6, c = pos & 63;
    gld16(apk + (((long)n * 512 + y0 + r) * 512 + x0 + c) * 32 + sq * 8,
          &ApS[u << 9]);
  }
  if (wv < 4) gld16(wk + spos * 32 + sq * 8, &BwS[wv << 9]);
  __syncthreads();

  f32x4_t acc[8][4];
#pragma unroll
  for (int mt = 0; mt < 8; ++mt)
#pragma unroll
    for (int nt = 0; nt < 4; ++nt) acc[mt][nt] = (f32x4_t)0.0f;

  bf16x8_t bf[4];
#pragma unroll
  for (int nt = 0; nt < 4; ++nt)
    bf[nt] = *(const bf16x8_t*)&BwS[(nt * 16 + l15) * 32 + quad * 8];
#pragma unroll
  for (int mt = 0; mt < 8; ++mt) {
    const int rl = 2 * wv + (mt >> 2);
    const int pl = (mt & 3) * 16 + l15;
    const bf16x8_t a = *(const bf16x8_t*)&ApS[(rl * 64 + pl) * 32 + quad * 8];
#pragma unroll
    for (int nt = 0; nt < 4; ++nt)
      acc[mt][nt] = __builtin_amdgcn_mfma_f32_16x16x32_bf16(a, bf[nt],
                                                            acc[mt][nt], 0, 0, 0);
  }

  float bv[4];
#pragma unroll
  for (int nt = 0; nt < 4; ++nt) bv[nt] = bias[nt * 16 + l15];

  __syncthreads();
  unsigned char* O8 = (unsigned char*)ApS;
#pragma unroll
  for (int mt = 0; mt < 8; ++mt) {
    const int ry = 2 * wv + (mt >> 2);
#pragma unroll
    for (int nt = 0; nt < 4; ++nt) {
      const int col = nt * 16 + l15;
#pragma unroll
      for (int reg = 0; reg < 4; ++reg) {
        int px = (mt & 3) * 16 + quad * 4 + reg;
        float v = fmaxf(acc[mt][nt][reg] + bv[nt], 0.0f);
        O8[((ry << 6) + px) * 64 + col] = f2fp8(v);
      }
    }
  }
  __syncthreads();
#pragma unroll
  for (int j = 0; j < 8; ++j) {
    int L = (j * 256 + tid) << 4;
    int x = (L >> 6) & 63;
    int cq = L & 63;
    *(uint4*)(out + (((long)n * 512 + y0 + j) * 512 + x0 + x) * 64 + cq) =
        *(const uint4*)&O8[L];
  }
}

// ---------------------------------------------------------------------------
// conv_f8 v6: 4-row block, wave = (row-pair pr, co-half ch). acc 64 regs,
// A-tile 25.6KB, 3 blocks/CU. MX MFMA K=64 per tap. (r5/r8-proven)
// ---------------------------------------------------------------------------
__global__ __launch_bounds__(256, 3) void conv_f8(
    const unsigned char* __restrict__ act, const unsigned char* __restrict__ wp,
    const float* __restrict__ bias, unsigned char* __restrict__ out,
    const unsigned char* __restrict__ zp, int Cin, int Cout, int H, int W) {
  __shared__ __align__(16) unsigned char ApS[400 * 64];
  const int tid = threadIdx.x;
  const int lane = tid & 63;
  const int wv = tid >> 6;
  const int l31 = lane & 31;
  const int h = lane >> 5;
  const int pr = wv & 1;   // row pair: rows 2pr, 2pr+1
  const int ch = wv >> 1;  // co half: ch*32
  const int coB = Cout >> 6;
  const int n = blockIdx.z / coB;
  const int co0 = (blockIdx.z % coB) << 6;
  const int x0 = blockIdx.x << 6;
  const int y0 = blockIdx.y << 2;
  const int spos = lane >> 2;
  const int sc = lane & 3;

  f32x16_t acc[2][2];
#pragma unroll
  for (int dr = 0; dr < 2; ++dr)
#pragma unroll
    for (int mh = 0; mh < 2; ++mh) acc[dr][mh] = (f32x16_t)0.0f;

  for (int cb = 0; cb < Cin; cb += 64) {
    if (cb) __syncthreads();  // guard ApS reuse
    for (int u = wv; u < 25; u += 4) {
      int pos = (u << 4) + spos;
      int q = sc ^ ((pos >> 1) & 3);  // inverse swizzle on the SOURCE
      int r = pos / 66, c = pos - r * 66;
      int gy = y0 - 1 + r, gx = x0 - 1 + c;
      const unsigned char* src = zp;
      if (pos < 396 && gy >= 0 && gy < H && gx >= 0 && gx < W)
        src = act + ((long)((long)n * H + gy) * W + gx) * Cin + cb + (q << 4);
      gld16(src, &ApS[u << 10]);
    }
    __syncthreads();

    const unsigned char* wl =
        wp + ((long)(co0 + (ch << 5) + l31)) * Cin + cb + (h << 5);
#pragma unroll
    for (int dx = 0; dx < 3; ++dx) {
      i32x8_t Af[2][4];
#pragma unroll
      for (int mh = 0; mh < 2; ++mh)
#pragma unroll
        for (int ri = 0; ri < 4; ++ri)
          Af[mh][ri] =
              ld_frag(ApS, (2 * pr + ri) * 66 + mh * 32 + l31 + dx, h);
#pragma unroll
      for (int dy = 0; dy < 3; ++dy) {
        const int o = dy * 3 + dx;
        i32x8_t Bf = ld32g(wl + (long)o * Cout * Cin);
#pragma unroll
        for (int dr = 0; dr < 2; ++dr)
#pragma unroll
          for (int mh = 0; mh < 2; ++mh)
            acc[dr][mh] = __builtin_amdgcn_mfma_scale_f32_32x32x64_f8f6f4(
                Af[mh][dr + dy], Bf, acc[dr][mh], 0, 0, 0,
                0x7F7F7F7F, 0, 0x7F7F7F7F);
      }
    }
  }

  const float bv = bias[co0 + (ch << 5) + l31];

  // LDS bounce: ApS reused as fp8 tile [ry 4][x 64][co 64] = 16KB.
  __syncthreads();
#pragma unroll
  for (int dr = 0; dr < 2; ++dr) {
    const int ry = 2 * pr + dr;
#pragma unroll
    for (int mh = 0; mh < 2; ++mh) {
#pragma unroll
      for (int reg = 0; reg < 16; ++reg) {
        int rowM = (reg & 3) + 8 * (reg >> 2) + 4 * h;
        int x = mh * 32 + rowM;
        float v = fmaxf(acc[dr][mh][reg] + bv, 0.0f);
        ApS[((ry << 6) + x) * 64 + (ch << 5) + l31] = f2fp8(v);
      }
    }
  }
  __syncthreads();
#pragma unroll
  for (int j = 0; j < 4; ++j) {
    int L = (j * 256 + tid) << 4;
    int ry = L >> 12;
    int x = (L >> 6) & 63;
    int cq = L & 63;
    *(uint4*)(out + (((long)n * H + y0 + ry) * W + x0 + x) * Cout + co0 + cq) =
        *(const uint4*)&ApS[L];
  }
}

// conv_f8p v6: conv_f8 + fused 2x2 maxpool; wide dual-store via LDS bounce.
// outF may be nullptr (fp8 output unused, e.g. last layer).
__global__ __launch_bounds__(256, 3) void conv_f8p(
    const unsigned char* __restrict__ act, const unsigned char* __restrict__ wp,
    const float* __restrict__ bias, unsigned char* __restrict__ outF,
    __hip_bfloat16* __restrict__ outB, const unsigned char* __restrict__ zp,
    int Cin, int Cout, int H, int W) {
  __shared__ __align__(16) unsigned char ApS[400 * 64];
  const int tid = threadIdx.x;
  const int lane = tid & 63;
  const int wv = tid >> 6;
  const int l31 = lane & 31;
  const int h = lane >> 5;
  const int pr = wv & 1;
  const int ch = wv >> 1;
  const int coB = Cout >> 6;
  const int n = blockIdx.z / coB;
  const int co0 = (blockIdx.z % coB) << 6;
  const int x0g = blockIdx.x << 6;
  const int y0 = blockIdx.y << 2;
  const int spos = lane >> 2;
  const int sc = lane & 3;

  f32x16_t acc[2][2];
#pragma unroll
  for (int dr = 0; dr < 2; ++dr)
#pragma unroll
    for (int mh = 0; mh < 2; ++mh) acc[dr][mh] = (f32x16_t)0.0f;

  for (int cb = 0; cb < Cin; cb += 64) {
    if (cb) __syncthreads();
    for (int u = wv; u < 25; u += 4) {
      int pos = (u << 4) + spos;
      int q = sc ^ ((pos >> 1) & 3);
      int r = pos / 66, c = pos - r * 66;
      int gy = y0 - 1 + r, gx = x0g - 1 + c;
      const unsigned char* src = zp;
      if (pos < 396 && gy >= 0 && gy < H && gx >= 0 && gx < W)
        src = act + ((long)((long)n * H + gy) * W + gx) * Cin + cb + (q << 4);
      gld16(src, &ApS[u << 10]);
    }
    __syncthreads();

    const unsigned char* wl =
        wp + ((long)(co0 + (ch << 5) + l31)) * Cin + cb + (h << 5);
#pragma unroll
    for (int dx = 0; dx < 3; ++dx) {
      i32x8_t Af[2][4];
#pragma unroll
      for (int mh = 0; mh < 2; ++mh)
#pragma unroll
        for (int ri = 0; ri < 4; ++ri)
          Af[mh][ri] =
              ld_frag(ApS, (2 * pr + ri) * 66 + mh * 32 + l31 + dx, h);
#pragma unroll
      for (int dy = 0; dy < 3; ++dy) {
        const int o = dy * 3 + dx;
        i32x8_t Bf = ld32g(wl + (long)o * Cout * Cin);
#pragma unroll
        for (int dr = 0; dr < 2; ++dr)
#pragma unroll
          for (int mh = 0; mh < 2; ++mh)
            acc[dr][mh] = __builtin_amdgcn_mfma_scale_f32_32x32x64_f8f6f4(
                Af[mh][dr + dy], Bf, acc[dr][mh], 0, 0, 0,
                0x7F7F7F7F, 0, 0x7F7F7F7F);
      }
    }
  }

  const int Ho = H >> 1, Wo = W >> 1;
  const int ho0 = blockIdx.y << 1;
  const int wo0 = blockIdx.x << 5;
  const float bv = bias[co0 + (ch << 5) + l31];

  // LDS bounce: fp8 tile [ho 2][wo 32][co 64] = 4KB, bf16 same layout 8KB.
  __syncthreads();
  unsigned char* F8 = ApS;
  __hip_bfloat16* BB = (__hip_bfloat16*)(ApS + 4096);
#pragma unroll
  for (int mh = 0; mh < 2; ++mh) {
#pragma unroll
    for (int p8 = 0; p8 < 8; ++p8) {
      const int reg = 2 * p8;  // (reg,reg+1) = x-adjacent pair
      float m0 = fmaxf(fmaxf(acc[0][mh][reg], acc[0][mh][reg + 1]),
                       fmaxf(acc[1][mh][reg], acc[1][mh][reg + 1]));
      float v = fmaxf(m0 + bv, 0.0f);
      int rowM = (reg & 3) + 8 * (reg >> 2) + 4 * h;
      int wo = mh * 16 + (rowM >> 1);  // 0..31
      int off = ((pr * 32 + wo) << 6) + (ch << 5) + l31;
      if (outF) F8[off] = f2fp8(v);
      BB[off] = __float2bfloat16(v);
    }
  }
  __syncthreads();
  if (outF) {
    int L = tid << 4;
    int hl = L >> 11;
    int wo = (L >> 6) & 31;
    int cq = L & 63;
    *(uint4*)(outF + (((long)n * Ho + ho0 + hl) * Wo + wo0 + wo) * Cout + co0 +
              cq) = *(const uint4*)&F8[L];
  }
#pragma unroll
  for (int j = 0; j < 2; ++j) {
    int S = (j * 256 + tid) << 3;  // short index
    int hl = S >> 11;
    int wo = (S >> 6) & 31;
    int cq = S & 63;
    *(uint4*)(outB + (((long)n * Ho + ho0 + hl) * Wo + wo0 + wo) * Cout + co0 +
              cq) = *(const uint4*)&BB[S];
  }
}

// NHWC [j][Ho][Wo][C] -> col-major planar [(j*C+c)][Wo][Ho]. (r10-proven)
__global__ __launch_bounds__(256) void transpose_k(
    const __hip_bfloat16* __restrict__ in, __hip_bfloat16* __restrict__ out,
    int C, int Ho, int Wo) {
  const int cl = threadIdx.x & 31;
  const int wl = threadIdx.x >> 5;
  const int cg = C >> 5;
  const int j = blockIdx.z / cg;
  const int c = (blockIdx.z % cg) * 32 + cl;
  const int wo = blockIdx.x * 8 + wl;
  const int ho0 = blockIdx.y * 8;
  __align__(16) __hip_bfloat16 res[8];
#pragma unroll
  for (int i = 0; i < 8; ++i)
    res[i] = in[(((long)j * Ho + ho0 + i) * Wo + wo) * C + c];
  *(uint4*)&out[((long)(j * C + c) * Wo + wo) * Ho + ho0] =
      *(const uint4*)res;
}

// l_perc partial: sum |cur - gt| over 8*M8 bf16 elements -> slots[2].
// gt repeats every gN 16B-groups (merged multi-stream compare).
__global__ __launch_bounds__(256) void perc_kernel(
    const __hip_bfloat16* __restrict__ gt, const __hip_bfloat16* __restrict__ cur,
    int M8, int gN, float* __restrict__ slots) {
  __shared__ float s4[4];
  const uint4* g4 = (const uint4*)gt;
  const uint4* c4 = (const uint4*)cur;
  float acc = 0.0f;
  for (int i = blockIdx.x * 256 + threadIdx.x; i < M8; i += gridDim.x * 256) {
    int ig = (i >= gN) ? i - gN : i;
    uint4 g = g4[ig], c = c4[i];
    const unsigned* gu = (const unsigned*)&g;
    const unsigned* cu = (const unsigned*)&c;
#pragma unroll
    for (int k = 0; k < 4; ++k) {
      float g0 = __uint_as_float(gu[k] << 16);
      float g1 = __uint_as_float(gu[k] & 0xffff0000u);
      float c0 = __uint_as_float(cu[k] << 16);
      float c1 = __uint_as_float(cu[k] & 0xffff0000u);
      acc += fabsf(c0 - g0) + fabsf(c1 - g1);
    }
  }
  float r = blk_sum256(acc, s4);
  if (threadIdx.x == 0) atomicAdd(&slots[2], r);
}

// Style partial via bf16 MFMA (r5-proven). Inputs col-major planar bf16.
// gt planes repeat every gtm z-planes (merged multi-stream compare).
template <int BM>
__global__ __launch_bounds__(256) void gram_mfma(
    const __hip_bfloat16* __restrict__ gt_p,
    const __hip_bfloat16* __restrict__ cur_p, int Wp, int Hp, int gtm,
    float fscale, float* __restrict__ slots) {
  constexpr int COLS = BM + 64;
  constexpr int WR = BM / 4;
  constexpr int MT = WR / 16;
  __shared__ __align__(16) short S[2 * COLS * 40];
  __shared__ float s4[4];
  const int tid = threadIdx.x;
  const int lane = tid & 63;
  const int wvi = tid >> 6;
  const int quad = lane >> 4, l15 = lane & 15;
  const int vt = blockIdx.x * 64;
  const int wt = blockIdx.y * BM;
  const long plane = (long)blockIdx.z * Wp * Hp;
  const long plane_g = (long)(blockIdx.z % gtm) * Wp * Hp;
  const __hip_bfloat16* bases[2] = {gt_p + plane_g, cur_p + plane};

  f32x4_t acc[2][MT][4];
#pragma unroll
  for (int t = 0; t < 2; ++t)
#pragma unroll
    for (int mt = 0; mt < MT; ++mt)
#pragma unroll
      for (int nt = 0; nt < 4; ++nt) acc[t][mt][nt] = (f32x4_t)0.0f;

  const int nchunk = 2 * COLS * 4;
  for (int h0 = 0; h0 < Hp; h0 += 32) {
    for (int e = tid; e < nchunk; e += 256) {
      int chunk = e & 3;
      int colt = e >> 2;
      int t = colt / COLS;
      int col = colt - t * COLS;
      int sc = (col < BM) ? (wt + col) : (vt + col - BM);
      uint4 v = *(const uint4*)(bases[t] + (long)sc * Hp + h0 + chunk * 8);
      *(uint4*)&S[(t * COLS + col) * 40 + chunk * 8] = v;
    }
    __syncthreads();
#pragma unroll
    for (int t = 0; t < 2; ++t) {
      bf16x8_t bf[4];
#pragma unroll
      for (int nt = 0; nt < 4; ++nt)
        bf[nt] = *(const bf16x8_t*)&S[(t * COLS + BM + nt * 16 + l15) * 40 +
                                      quad * 8];
#pragma unroll
      for (int mt = 0; mt < MT; ++mt) {
        bf16x8_t a = *(const bf16x8_t*)&S[(t * COLS + wvi * WR + mt * 16 + l15) *
                                              40 + quad * 8];
#pragma unroll
        for (int nt = 0; nt < 4; ++nt)
          acc[t][mt][nt] = __builtin_amdgcn_mfma_f32_16x16x32_bf16(
              a, bf[nt], acc[t][mt][nt], 0, 0, 0);
      }
    }
    __syncthreads();
  }

  float local = 0.0f;
#pragma unroll
  for (int mt = 0; mt < MT; ++mt)
#pragma unroll
    for (int nt = 0; nt < 4; ++nt)
#pragma unroll
      for (int reg = 0; reg < 4; ++reg)
        local += fabsf(acc[1][mt][nt][reg] - acc[0][mt][nt][reg]);
  float r = blk_sum256(local, s4);
  if (tid == 0) atomicAdd(&slots[3], r * fscale);
}

__global__ void combine_kernel(const float* __restrict__ slots,
                               float* __restrict__ out) {
  if (threadIdx.x == 0) {
    const float Nn = 1572864.0f;
    const float Nigt = 8388608.0f;
    out[0] = 2.0f * slots[0] / Nn + slots[1] / Nn + slots[2] / Nigt + slots[3];
  }
}

extern "C" void kernel_launch(void* const* d_in, const int* in_sizes, int n_in,
                              void* d_out, int out_size, void* d_ws,
                              size_t ws_size, hipStream_t stream) {
  (void)in_sizes; (void)n_in; (void)out_size;
  const float* igt = (const float*)d_in[0];
  const float* iout = (const float*)d_in[1];
  const float* mask = (const float*)d_in[2];
  const float* w[7];
  const float* b[7];
  for (int i = 0; i < 7; ++i) {
    w[i] = (const float*)d_in[3 + 2 * i];
    b[i] = (const float*)d_in[4 + 2 * i];
  }
  float* slots = (float*)d_ws;
  const unsigned char* zp = (const unsigned char*)d_ws + 64;  // 16B zeros

  unsigned char* wpk = (unsigned char*)((char*)d_ws + 256);
  __hip_bfloat16* w1k = (__hip_bfloat16*)((char*)d_ws + 256 + 1732608);
  // weights end at byte 1,736,960

  const size_t NEED2 = 194674944ULL;
  const int NB = (ws_size >= NEED2) ? 2 : 1;
  const int B3 = 3 * NB;
  const size_t M = (size_t)NB;  // scale factor

  char* base = (char*)d_ws + 1736960;
  // Region A (Apk region): M*16,777,216
  __hip_bfloat16* Apk = (__hip_bfloat16*)base;             // stage-1 im2col
  unsigned char* P1N8 = (unsigned char*)base;              // after conv1m done
  __hip_bfloat16* P2T = (__hip_bfloat16*)base;             // after L3 done
  // Region B (Y1 region): at M*16,777,216, size M*50,331,648
  char* Y1base = base + M * 16777216;
  unsigned char* Y1 = (unsigned char*)Y1base;              // Y1[3] contiguous
  __hip_bfloat16* pgT1 = (__hip_bfloat16*)Y1base;          // after L2 done
  __hip_bfloat16* pcT1 = (__hip_bfloat16*)(Y1base + M * 8388608);
  unsigned char* P2N8 = (unsigned char*)(Y1base + M * 25165824);
  __hip_bfloat16* P2Nb = (__hip_bfloat16*)(Y1base + M * 31457280);
  __hip_bfloat16* P3Nb = (__hip_bfloat16*)Y1base;          // after P1 gram done
  __hip_bfloat16* P3T = (__hip_bfloat16*)(Y1base + M * 6291456);
  // Region C (P1Nb region): at M*67,108,864, size M*25,165,824
  char* Cbase = base + M * 67108864;
  __hip_bfloat16* P1Nb = (__hip_bfloat16*)Cbase;           // 3 streams contig
  unsigned char* T = (unsigned char*)Cbase;                // after transpose P1
  unsigned char* Y5 = (unsigned char*)Cbase;               // after L4 done
  unsigned char* Y6 = (unsigned char*)(Cbase + M * 12582912);
  // End of workspace use: base + M*92,274,688 = 186,286,336 bytes < NEED2.

  const float fs1 = (float)(1.0 / (4194304.0 * 4096.0));
  const float fs2 = (float)(1.0 / (2097152.0 * 16384.0));
  const float fs3 = (float)(1.0 / (1048576.0 * 65536.0));

  init_slots<<<1, 64, 0, stream>>>(slots);
  // Merged prologue: 6x pack_w + pack_w1 + l1 in ONE dispatch.
  pack_all<<<2004, 256, 0, stream>>>(w[0], w[1], w[2], w[3], w[4], w[5], w[6],
                                     igt, iout, mask, wpk, w1k, slots);

  for (int n0 = 0; n0 < 2; n0 += NB) {
    // Stage 1: all 3 streams through conv1 first (Y1[3] contiguous) ...
    for (int s = 0; s < 3; ++s) {
      pack2_kernel<<<NB * 1024, 256, 0, stream>>>(igt, iout, mask, Apk, s, n0,
                                                  NB);
      conv1m<<<dim3(8, 64, NB), 256, 0, stream>>>(
          Apk, w1k, b[0], Y1 + (size_t)s * M * 16777216);
    }
    // ... then ONE merged L2 conv+pool over 3*NB images.
    conv_f8p<<<dim3(8, 128, 3 * NB), 256, 0, stream>>>(
        Y1, wpk + 0, b[1], P1N8, P1Nb, zp, 64, 64, 512, 512);
    // ONE merged transpose: P1Nb[3*NB] -> pgT1|pcT1 (contiguous planes).
    transpose_k<<<dim3(32, 32, 3 * NB * 2), 256, 0, stream>>>(P1Nb, pgT1, 64,
                                                              256, 256);
    // Merged perc+gram over both compare pairs (gt repeats via gN/gtm).
    perc_kernel<<<304, 256, 0, stream>>>(pgT1, pcT1, NB * 1048576,
                                         NB * 524288, slots);
    gram_mfma<128><<<dim3(4, 2, NB * 128), 256, 0, stream>>>(
        pgT1, pcT1, 256, 256, NB * 64, fs1, slots);

    // Stage 2.
    conv_f8<<<dim3(4, 64, B3 * 2), 256, 0, stream>>>(
        P1N8, wpk + 36864, b[2], T, zp, 64, 128, 256, 256);
    conv_f8p<<<dim3(4, 64, B3 * 2), 256, 0, stream>>>(
        T, wpk + 110592, b[3], P2N8, P2Nb, zp, 128, 128, 256, 256);
    transpose_k<<<dim3(16, 16, B3 * 4), 256, 0, stream>>>(P2Nb, P2T, 128, 128,
                                                          128);
    perc_kernel<<<304, 256, 0, stream>>>(P2T, P2T + M * 2097152, NB * 524288,
                                         NB * 262144, slots);
    gram_mfma<128><<<dim3(2, 1, NB * 256), 256, 0, stream>>>(
        P2T, P2T + M * 2097152, 128, 128, NB * 128, fs2, slots);

    // Stage 3.
    conv_f8<<<dim3(2, 32, B3 * 4), 256, 0, stream>>>(
        P2N8, wpk + 258048, b[4], Y5, zp, 128, 256, 128, 128);
    conv_f8<<<dim3(2, 32, B3 * 4), 256, 0, stream>>>(
        Y5, wpk + 552960, b[5], Y6, zp, 256, 256, 128, 128);
    conv_f8p<<<dim3(2, 32, B3 * 4), 256, 0, stream>>>(
        Y6, wpk + 1142784, b[6], (unsigned char*)nullptr, P3Nb, zp, 256, 256,
        128, 128);
    transpose_k<<<dim3(8, 8, B3 * 8), 256, 0, stream>>>(P3Nb, P3T, 256, 64, 64);
    perc_kernel<<<304, 256, 0, stream>>>(P3T, P3T + M * 1048576, NB * 262144,
                                         NB * 131072, slots);
    gram_mfma<64><<<dim3(1, 1, NB * 512), 256, 0, stream>>>(
        P3T, P3T + M * 1048576, 64, 64, NB * 256, fs3, slots);
  }

  combine_kernel<<<1, 64, 0, stream>>>(slots, (float*)d_out);
}

// Round 12
// 724.948 us; speedup vs baseline: 1.3063x; 1.0388x over previous
//
#include <hip/hip_runtime.h>
#include <hip/hip_bf16.h>

// ---------------------------------------------------------------------------
// VGG16 perceptual+style inpainting loss.
// v12 = v11 (753us, best) + stage-1 fusion: pack2 (im2col -> HBM) + conv1m
// (HBM -> LDS GEMM) replaced by ONE conv1f kernel (z = 3*NB streams) that
// builds the im2col tile IN-KERNEL straight into LDS (identical mask/border/
// bf16 path -> bit-identical numerics). Removes 96MB+96MB of im2col HBM
// round-trip and 5 dispatches.
// All other kernels verbatim v11: conv_f8/conv_f8p (4-row blocks, 3 blk/CU,
// MX-scaled fp8 MFMA scale=1.0, gld16 A-stage w/ inverse-swizzled source +
// zero-page halo, W global->reg, LDS-bounce dwordx4 epilogues), merged L2
// (z=3NB), merged P1 transpose, merged perc/gram via gN/gtm, L7
// outF=nullptr, pack_all prologue. Workspace layout identical (Apk region
// now unused until P1N8).
// ---------------------------------------------------------------------------

typedef __attribute__((ext_vector_type(8))) short bf16x8_t;
typedef __attribute__((ext_vector_type(4))) float f32x4_t;
typedef __attribute__((ext_vector_type(16))) float f32x16_t;
typedef __attribute__((ext_vector_type(8))) int i32x8_t;

typedef const __attribute__((address_space(1))) void* gas_t;
typedef __attribute__((address_space(3))) void* las_t;

__device__ __forceinline__ void gld16(const void* g, void* l) {
  __builtin_amdgcn_global_load_lds((gas_t)g, (las_t)l, 16, 0, 0);
}

__device__ __forceinline__ unsigned char f2fp8(float v) {
  return (unsigned char)(__builtin_amdgcn_cvt_pk_fp8_f32(v, v, 0, false) & 0xff);
}

// Read one 32B fragment (logical chunks 2h,2h+1 of a 64B row) from a
// chunk-swizzled LDS tile. Swizzle: physical chunk = logical ^ ((row>>1)&3).
__device__ __forceinline__ i32x8_t ld_frag(const unsigned char* lds, int row,
                                           int h) {
  const int sw = (row >> 1) & 3;
  const unsigned char* base = lds + row * 64;
  uint4 lo = *(const uint4*)(base + (((2 * h) ^ sw) << 4));
  uint4 hi = *(const uint4*)(base + (((2 * h + 1) ^ sw) << 4));
  i32x8_t r;
  r[0] = lo.x; r[1] = lo.y; r[2] = lo.z; r[3] = lo.w;
  r[4] = hi.x; r[5] = hi.y; r[6] = hi.z; r[7] = hi.w;
  return r;
}

// 32 contiguous bytes global -> i32x8 (B fragment direct from L1/L2).
__device__ __forceinline__ i32x8_t ld32g(const unsigned char* p) {
  uint4 lo = *(const uint4*)p;
  uint4 hi = *(const uint4*)(p + 16);
  i32x8_t r;
  r[0] = lo.x; r[1] = lo.y; r[2] = lo.z; r[3] = lo.w;
  r[4] = hi.x; r[5] = hi.y; r[6] = hi.z; r[7] = hi.w;
  return r;
}

__device__ __forceinline__ float blk_sum256(float v, float* s4) {
#pragma unroll
  for (int o = 32; o > 0; o >>= 1) v += __shfl_down(v, o);
  int w = threadIdx.x >> 6;
  if ((threadIdx.x & 63) == 0) s4[w] = v;
  __syncthreads();
  float r = s4[0] + s4[1] + s4[2] + s4[3];
  __syncthreads();
  return r;
}

__global__ void init_slots(float* slots) {
  if (threadIdx.x < 32) slots[threadIdx.x] = 0.0f;  // slots[0..7] + zero-page
}

// ---------------------------------------------------------------------------
// pack_all: merged prologue. Block ranges:
//  [0,1692)    pack_w for layers 0..5 (fp32 OIHW -> fp8 [tap][cout][cin])
//  [1692,1700) pack_w1 (conv1 weights -> bf16 [co][32])
//  [1700,2004) l1_kernel (hole/valid L1 partials -> slots[0..1])
// ---------------------------------------------------------------------------
__global__ __launch_bounds__(256) void pack_all(
    const float* __restrict__ w1, const float* __restrict__ w2,
    const float* __restrict__ w3, const float* __restrict__ w4,
    const float* __restrict__ w5, const float* __restrict__ w6,
    const float* __restrict__ w7, const float* __restrict__ igt,
    const float* __restrict__ iout, const float* __restrict__ mask,
    unsigned char* __restrict__ wpk, __hip_bfloat16* __restrict__ w1k,
    float* __restrict__ slots) {
  __shared__ float s4[4];
  const int b = blockIdx.x;
  if (b < 1692) {
    int start, Cin, Cout;
    long off;
    const float* w;
    if (b < 36)        { start = 0;    Cin = 64;  Cout = 64;  off = 0;       w = w2; }
    else if (b < 108)  { start = 36;   Cin = 64;  Cout = 128; off = 36864;   w = w3; }
    else if (b < 252)  { start = 108;  Cin = 128; Cout = 128; off = 110592;  w = w4; }
    else if (b < 540)  { start = 252;  Cin = 128; Cout = 256; off = 258048;  w = w5; }
    else if (b < 1116) { start = 540;  Cin = 256; Cout = 256; off = 552960;  w = w6; }
    else               { start = 1116; Cin = 256; Cout = 256; off = 1142784; w = w7; }
    unsigned char* wp = wpk + off;
    int i = (b - start) * 256 + threadIdx.x;
    int c4n = Cin >> 2;
    int o = i % 9;
    int rem = i / 9;
    int c4 = rem % c4n;
    int co = rem / c4n;
    int dy = o / 3, dx = o % 3;
    unsigned r = 0;
#pragma unroll
    for (int k = 0; k < 4; ++k) {
      int ci = c4 * 4 + k;
      float v = w[((co * Cin + ci) * 3 + dy) * 3 + dx];
      r |= (unsigned)f2fp8(v) << (8 * k);
    }
    *(unsigned*)(wp + ((long)(o * Cout + co)) * Cin + c4 * 4) = r;
  } else if (b < 1700) {
    int i = (b - 1692) * 256 + threadIdx.x;  // < 2048
    int co = i >> 5, k = i & 31;
    float v = 0.0f;
    if (k < 27) {
      int dy = k / 9, r = k - dy * 9;
      int dx = r / 3, ci = r - dx * 3;
      v = w1[((co * 3 + ci) * 3 + dy) * 3 + dx];
    }
    w1k[i] = __float2bfloat16(v);
  } else {
    int vb = b - 1700;
    float ah = 0.0f, av = 0.0f;
    for (int idx = vb * 256 + threadIdx.x; idx < 1572864; idx += 304 * 256) {
      int pix = idx & 262143;
      int n = idx / 786432;
      float mk = mask[n * 262144 + pix];
      bool m = (mk != 0.0f);
      float d = fabsf(iout[idx] - igt[idx]);
      if (m) av += d; else ah += d;
    }
    float r = blk_sum256(ah, s4);
    if (threadIdx.x == 0) atomicAdd(&slots[0], r);
    r = blk_sum256(av, s4);
    if (threadIdx.x == 0) atomicAdd(&slots[1], r);
  }
}

// ---------------------------------------------------------------------------
// conv1f: FUSED im2col + K=32 bf16 MFMA GEMM -> fp8 NHWC Y1, all 3 streams
// in one dispatch (z = s*NB + nl). Each thread builds 2 pixels' im2col rows
// (identical mask/border/bf16 path as the old pack2) straight into LDS.
// GEMM + LDS-bounce epilogue identical to the proven conv1m.
// ---------------------------------------------------------------------------
__global__ __launch_bounds__(256, 2) void conv1f(
    const float* __restrict__ igt, const float* __restrict__ iout,
    const float* __restrict__ mask, const __hip_bfloat16* __restrict__ wk,
    const float* __restrict__ bias, unsigned char* __restrict__ outb,
    int n0, int NB, long ystride) {
  __shared__ __align__(16) short ApS[512 * 32];
  __shared__ __align__(16) short BwS[64 * 32];
  const int tid = threadIdx.x;
  const int lane = tid & 63;
  const int wv = tid >> 6;
  const int quad = lane >> 4, l15 = lane & 15;
  const int s = blockIdx.z / NB;
  const int nl = blockIdx.z % NB;
  const int sample = n0 + nl;
  const int x0 = blockIdx.x << 6;
  const int y0 = blockIdx.y << 3;

  // B: 64 entries x 64B = 4 slabs via gld16.
  if (wv < 4) gld16(wk + (lane >> 2) * 32 + (lane & 3) * 8, &BwS[wv << 9]);

  // A: in-kernel im2col, 2 pixels per thread (pack2-identical values).
#pragma unroll
  for (int t = 0; t < 2; ++t) {
    int pix = tid + t * 256;  // 0..511
    int r = pix >> 6, c = pix & 63;
    int y = y0 + r, x = x0 + c;
    __align__(16) __hip_bfloat16 buf[32];
#pragma unroll
    for (int k = 27; k < 32; ++k) buf[k] = __float2bfloat16(0.0f);
    for (int dy = 0; dy < 3; ++dy)
      for (int dx = 0; dx < 3; ++dx) {
        int gy = y - 1 + dy, gx = x - 1 + dx;
        bool inb = (gy >= 0 && gy < 512 && gx >= 0 && gx < 512);
        int p = gy * 512 + gx;
        bool useG;
        if (s == 0) useG = true;
        else if (s == 1) useG = false;
        else useG = inb && (mask[sample * 262144 + (inb ? p : 0)] != 0.0f);
        const float* src = useG ? igt : iout;
#pragma unroll
        for (int ci = 0; ci < 3; ++ci) {
          float v = inb ? src[sample * 786432 + ci * 262144 + p] : 0.0f;
          buf[dy * 9 + dx * 3 + ci] = __float2bfloat16(v);
        }
      }
#pragma unroll
    for (int q = 0; q < 4; ++q)
      *(uint4*)&ApS[pix * 32 + q * 8] = *(const uint4*)&buf[q * 8];
  }
  __syncthreads();

  f32x4_t acc[8][4];
#pragma unroll
  for (int mt = 0; mt < 8; ++mt)
#pragma unroll
    for (int nt = 0; nt < 4; ++nt) acc[mt][nt] = (f32x4_t)0.0f;

  bf16x8_t bf[4];
#pragma unroll
  for (int nt = 0; nt < 4; ++nt)
    bf[nt] = *(const bf16x8_t*)&BwS[(nt * 16 + l15) * 32 + quad * 8];
#pragma unroll
  for (int mt = 0; mt < 8; ++mt) {
    const int rl = 2 * wv + (mt >> 2);
    const int pl = (mt & 3) * 16 + l15;
    const bf16x8_t a = *(const bf16x8_t*)&ApS[(rl * 64 + pl) * 32 + quad * 8];
#pragma unroll
    for (int nt = 0; nt < 4; ++nt)
      acc[mt][nt] = __builtin_amdgcn_mfma_f32_16x16x32_bf16(a, bf[nt],
                                                            acc[mt][nt], 0, 0, 0);
  }

  float bv[4];
#pragma unroll
  for (int nt = 0; nt < 4; ++nt) bv[nt] = bias[nt * 16 + l15];

  __syncthreads();
  unsigned char* O8 = (unsigned char*)ApS;
#pragma unroll
  for (int mt = 0; mt < 8; ++mt) {
    const int ry = 2 * wv + (mt >> 2);
#pragma unroll
    for (int nt = 0; nt < 4; ++nt) {
      const int col = nt * 16 + l15;
#pragma unroll
      for (int reg = 0; reg < 4; ++reg) {
        int px = (mt & 3) * 16 + quad * 4 + reg;
        float v = fmaxf(acc[mt][nt][reg] + bv[nt], 0.0f);
        O8[((ry << 6) + px) * 64 + col] = f2fp8(v);
      }
    }
  }
  __syncthreads();
  unsigned char* out = outb + (long)s * ystride;
#pragma unroll
  for (int j = 0; j < 8; ++j) {
    int L = (j * 256 + tid) << 4;
    int x = (L >> 6) & 63;
    int cq = L & 63;
    *(uint4*)(out + (((long)nl * 512 + y0 + j) * 512 + x0 + x) * 64 + cq) =
        *(const uint4*)&O8[L];
  }
}

// ---------------------------------------------------------------------------
// conv_f8 v6: 4-row block, wave = (row-pair pr, co-half ch). acc 64 regs,
// A-tile 25.6KB, 3 blocks/CU. MX MFMA K=64 per tap. (r5/r8/r11-proven)
// ---------------------------------------------------------------------------
__global__ __launch_bounds__(256, 3) void conv_f8(
    const unsigned char* __restrict__ act, const unsigned char* __restrict__ wp,
    const float* __restrict__ bias, unsigned char* __restrict__ out,
    const unsigned char* __restrict__ zp, int Cin, int Cout, int H, int W) {
  __shared__ __align__(16) unsigned char ApS[400 * 64];
  const int tid = threadIdx.x;
  const int lane = tid & 63;
  const int wv = tid >> 6;
  const int l31 = lane & 31;
  const int h = lane >> 5;
  const int pr = wv & 1;   // row pair: rows 2pr, 2pr+1
  const int ch = wv >> 1;  // co half: ch*32
  const int coB = Cout >> 6;
  const int n = blockIdx.z / coB;
  const int co0 = (blockIdx.z % coB) << 6;
  const int x0 = blockIdx.x << 6;
  const int y0 = blockIdx.y << 2;
  const int spos = lane >> 2;
  const int sc = lane & 3;

  f32x16_t acc[2][2];
#pragma unroll
  for (int dr = 0; dr < 2; ++dr)
#pragma unroll
    for (int mh = 0; mh < 2; ++mh) acc[dr][mh] = (f32x16_t)0.0f;

  for (int cb = 0; cb < Cin; cb += 64) {
    if (cb) __syncthreads();  // guard ApS reuse
    for (int u = wv; u < 25; u += 4) {
      int pos = (u << 4) + spos;
      int q = sc ^ ((pos >> 1) & 3);  // inverse swizzle on the SOURCE
      int r = pos / 66, c = pos - r * 66;
      int gy = y0 - 1 + r, gx = x0 - 1 + c;
      const unsigned char* src = zp;
      if (pos < 396 && gy >= 0 && gy < H && gx >= 0 && gx < W)
        src = act + ((long)((long)n * H + gy) * W + gx) * Cin + cb + (q << 4);
      gld16(src, &ApS[u << 10]);
    }
    __syncthreads();

    const unsigned char* wl =
        wp + ((long)(co0 + (ch << 5) + l31)) * Cin + cb + (h << 5);
#pragma unroll
    for (int dx = 0; dx < 3; ++dx) {
      i32x8_t Af[2][4];
#pragma unroll
      for (int mh = 0; mh < 2; ++mh)
#pragma unroll
        for (int ri = 0; ri < 4; ++ri)
          Af[mh][ri] =
              ld_frag(ApS, (2 * pr + ri) * 66 + mh * 32 + l31 + dx, h);
#pragma unroll
      for (int dy = 0; dy < 3; ++dy) {
        const int o = dy * 3 + dx;
        i32x8_t Bf = ld32g(wl + (long)o * Cout * Cin);
#pragma unroll
        for (int dr = 0; dr < 2; ++dr)
#pragma unroll
          for (int mh = 0; mh < 2; ++mh)
            acc[dr][mh] = __builtin_amdgcn_mfma_scale_f32_32x32x64_f8f6f4(
                Af[mh][dr + dy], Bf, acc[dr][mh], 0, 0, 0,
                0x7F7F7F7F, 0, 0x7F7F7F7F);
      }
    }
  }

  const float bv = bias[co0 + (ch << 5) + l31];

  // LDS bounce: ApS reused as fp8 tile [ry 4][x 64][co 64] = 16KB.
  __syncthreads();
#pragma unroll
  for (int dr = 0; dr < 2; ++dr) {
    const int ry = 2 * pr + dr;
#pragma unroll
    for (int mh = 0; mh < 2; ++mh) {
#pragma unroll
      for (int reg = 0; reg < 16; ++reg) {
        int rowM = (reg & 3) + 8 * (reg >> 2) + 4 * h;
        int x = mh * 32 + rowM;
        float v = fmaxf(acc[dr][mh][reg] + bv, 0.0f);
        ApS[((ry << 6) + x) * 64 + (ch << 5) + l31] = f2fp8(v);
      }
    }
  }
  __syncthreads();
#pragma unroll
  for (int j = 0; j < 4; ++j) {
    int L = (j * 256 + tid) << 4;
    int ry = L >> 12;
    int x = (L >> 6) & 63;
    int cq = L & 63;
    *(uint4*)(out + (((long)n * H + y0 + ry) * W + x0 + x) * Cout + co0 + cq) =
        *(const uint4*)&ApS[L];
  }
}

// conv_f8p v6: conv_f8 + fused 2x2 maxpool; wide dual-store via LDS bounce.
// outF may be nullptr (fp8 output unused, e.g. last layer).
__global__ __launch_bounds__(256, 3) void conv_f8p(
    const unsigned char* __restrict__ act, const unsigned char* __restrict__ wp,
    const float* __restrict__ bias, unsigned char* __restrict__ outF,
    __hip_bfloat16* __restrict__ outB, const unsigned char* __restrict__ zp,
    int Cin, int Cout, int H, int W) {
  __shared__ __align__(16) unsigned char ApS[400 * 64];
  const int tid = threadIdx.x;
  const int lane = tid & 63;
  const int wv = tid >> 6;
  const int l31 = lane & 31;
  const int h = lane >> 5;
  const int pr = wv & 1;
  const int ch = wv >> 1;
  const int coB = Cout >> 6;
  const int n = blockIdx.z / coB;
  const int co0 = (blockIdx.z % coB) << 6;
  const int x0g = blockIdx.x << 6;
  const int y0 = blockIdx.y << 2;
  const int spos = lane >> 2;
  const int sc = lane & 3;

  f32x16_t acc[2][2];
#pragma unroll
  for (int dr = 0; dr < 2; ++dr)
#pragma unroll
    for (int mh = 0; mh < 2; ++mh) acc[dr][mh] = (f32x16_t)0.0f;

  for (int cb = 0; cb < Cin; cb += 64) {
    if (cb) __syncthreads();
    for (int u = wv; u < 25; u += 4) {
      int pos = (u << 4) + spos;
      int q = sc ^ ((pos >> 1) & 3);
      int r = pos / 66, c = pos - r * 66;
      int gy = y0 - 1 + r, gx = x0g - 1 + c;
      const unsigned char* src = zp;
      if (pos < 396 && gy >= 0 && gy < H && gx >= 0 && gx < W)
        src = act + ((long)((long)n * H + gy) * W + gx) * Cin + cb + (q << 4);
      gld16(src, &ApS[u << 10]);
    }
    __syncthreads();

    const unsigned char* wl =
        wp + ((long)(co0 + (ch << 5) + l31)) * Cin + cb + (h << 5);
#pragma unroll
    for (int dx = 0; dx < 3; ++dx) {
      i32x8_t Af[2][4];
#pragma unroll
      for (int mh = 0; mh < 2; ++mh)
#pragma unroll
        for (int ri = 0; ri < 4; ++ri)
          Af[mh][ri] =
              ld_frag(ApS, (2 * pr + ri) * 66 + mh * 32 + l31 + dx, h);
#pragma unroll
      for (int dy = 0; dy < 3; ++dy) {
        const int o = dy * 3 + dx;
        i32x8_t Bf = ld32g(wl + (long)o * Cout * Cin);
#pragma unroll
        for (int dr = 0; dr < 2; ++dr)
#pragma unroll
          for (int mh = 0; mh < 2; ++mh)
            acc[dr][mh] = __builtin_amdgcn_mfma_scale_f32_32x32x64_f8f6f4(
                Af[mh][dr + dy], Bf, acc[dr][mh], 0, 0, 0,
                0x7F7F7F7F, 0, 0x7F7F7F7F);
      }
    }
  }

  const int Ho = H >> 1, Wo = W >> 1;
  const int ho0 = blockIdx.y << 1;
  const int wo0 = blockIdx.x << 5;
  const float bv = bias[co0 + (ch << 5) + l31];

  // LDS bounce: fp8 tile [ho 2][wo 32][co 64] = 4KB, bf16 same layout 8KB.
  __syncthreads();
  unsigned char* F8 = ApS;
  __hip_bfloat16* BB = (__hip_bfloat16*)(ApS + 4096);
#pragma unroll
  for (int mh = 0; mh < 2; ++mh) {
#pragma unroll
    for (int p8 = 0; p8 < 8; ++p8) {
      const int reg = 2 * p8;  // (reg,reg+1) = x-adjacent pair
      float m0 = fmaxf(fmaxf(acc[0][mh][reg], acc[0][mh][reg + 1]),
                       fmaxf(acc[1][mh][reg], acc[1][mh][reg + 1]));
      float v = fmaxf(m0 + bv, 0.0f);
      int rowM = (reg & 3) + 8 * (reg >> 2) + 4 * h;
      int wo = mh * 16 + (rowM >> 1);  // 0..31
      int off = ((pr * 32 + wo) << 6) + (ch << 5) + l31;
      if (outF) F8[off] = f2fp8(v);
      BB[off] = __float2bfloat16(v);
    }
  }
  __syncthreads();
  if (outF) {
    int L = tid << 4;
    int hl = L >> 11;
    int wo = (L >> 6) & 31;
    int cq = L & 63;
    *(uint4*)(outF + (((long)n * Ho + ho0 + hl) * Wo + wo0 + wo) * Cout + co0 +
              cq) = *(const uint4*)&F8[L];
  }
#pragma unroll
  for (int j = 0; j < 2; ++j) {
    int S = (j * 256 + tid) << 3;  // short index
    int hl = S >> 11;
    int wo = (S >> 6) & 31;
    int cq = S & 63;
    *(uint4*)(outB + (((long)n * Ho + ho0 + hl) * Wo + wo0 + wo) * Cout + co0 +
              cq) = *(const uint4*)&BB[S];
  }
}

// NHWC [j][Ho][Wo][C] -> col-major planar [(j*C+c)][Wo][Ho]. (r10-proven)
__global__ __launch_bounds__(256) void transpose_k(
    const __hip_bfloat16* __restrict__ in, __hip_bfloat16* __restrict__ out,
    int C, int Ho, int Wo) {
  const int cl = threadIdx.x & 31;
  const int wl = threadIdx.x >> 5;
  const int cg = C >> 5;
  const int j = blockIdx.z / cg;
  const int c = (blockIdx.z % cg) * 32 + cl;
  const int wo = blockIdx.x * 8 + wl;
  const int ho0 = blockIdx.y * 8;
  __align__(16) __hip_bfloat16 res[8];
#pragma unroll
  for (int i = 0; i < 8; ++i)
    res[i] = in[(((long)j * Ho + ho0 + i) * Wo + wo) * C + c];
  *(uint4*)&out[((long)(j * C + c) * Wo + wo) * Ho + ho0] =
      *(const uint4*)res;
}

// l_perc partial: sum |cur - gt| over 8*M8 bf16 elements -> slots[2].
// gt repeats every gN 16B-groups (merged multi-stream compare).
__global__ __launch_bounds__(256) void perc_kernel(
    const __hip_bfloat16* __restrict__ gt, const __hip_bfloat16* __restrict__ cur,
    int M8, int gN, float* __restrict__ slots) {
  __shared__ float s4[4];
  const uint4* g4 = (const uint4*)gt;
  const uint4* c4 = (const uint4*)cur;
  float acc = 0.0f;
  for (int i = blockIdx.x * 256 + threadIdx.x; i < M8; i += gridDim.x * 256) {
    int ig = (i >= gN) ? i - gN : i;
    uint4 g = g4[ig], c = c4[i];
    const unsigned* gu = (const unsigned*)&g;
    const unsigned* cu = (const unsigned*)&c;
#pragma unroll
    for (int k = 0; k < 4; ++k) {
      float g0 = __uint_as_float(gu[k] << 16);
      float g1 = __uint_as_float(gu[k] & 0xffff0000u);
      float c0 = __uint_as_float(cu[k] << 16);
      float c1 = __uint_as_float(cu[k] & 0xffff0000u);
      acc += fabsf(c0 - g0) + fabsf(c1 - g1);
    }
  }
  float r = blk_sum256(acc, s4);
  if (threadIdx.x == 0) atomicAdd(&slots[2], r);
}

// Style partial via bf16 MFMA (r5-proven). Inputs col-major planar bf16.
// gt planes repeat every gtm z-planes (merged multi-stream compare).
template <int BM>
__global__ __launch_bounds__(256) void gram_mfma(
    const __hip_bfloat16* __restrict__ gt_p,
    const __hip_bfloat16* __restrict__ cur_p, int Wp, int Hp, int gtm,
    float fscale, float* __restrict__ slots) {
  constexpr int COLS = BM + 64;
  constexpr int WR = BM / 4;
  constexpr int MT = WR / 16;
  __shared__ __align__(16) short S[2 * COLS * 40];
  __shared__ float s4[4];
  const int tid = threadIdx.x;
  const int lane = tid & 63;
  const int wvi = tid >> 6;
  const int quad = lane >> 4, l15 = lane & 15;
  const int vt = blockIdx.x * 64;
  const int wt = blockIdx.y * BM;
  const long plane = (long)blockIdx.z * Wp * Hp;
  const long plane_g = (long)(blockIdx.z % gtm) * Wp * Hp;
  const __hip_bfloat16* bases[2] = {gt_p + plane_g, cur_p + plane};

  f32x4_t acc[2][MT][4];
#pragma unroll
  for (int t = 0; t < 2; ++t)
#pragma unroll
    for (int mt = 0; mt < MT; ++mt)
#pragma unroll
      for (int nt = 0; nt < 4; ++nt) acc[t][mt][nt] = (f32x4_t)0.0f;

  const int nchunk = 2 * COLS * 4;
  for (int h0 = 0; h0 < Hp; h0 += 32) {
    for (int e = tid; e < nchunk; e += 256) {
      int chunk = e & 3;
      int colt = e >> 2;
      int t = colt / COLS;
      int col = colt - t * COLS;
      int sc = (col < BM) ? (wt + col) : (vt + col - BM);
      uint4 v = *(const uint4*)(bases[t] + (long)sc * Hp + h0 + chunk * 8);
      *(uint4*)&S[(t * COLS + col) * 40 + chunk * 8] = v;
    }
    __syncthreads();
#pragma unroll
    for (int t = 0; t < 2; ++t) {
      bf16x8_t bf[4];
#pragma unroll
      for (int nt = 0; nt < 4; ++nt)
        bf[nt] = *(const bf16x8_t*)&S[(t * COLS + BM + nt * 16 + l15) * 40 +
                                      quad * 8];
#pragma unroll
      for (int mt = 0; mt < MT; ++mt) {
        bf16x8_t a = *(const bf16x8_t*)&S[(t * COLS + wvi * WR + mt * 16 + l15) *
                                              40 + quad * 8];
#pragma unroll
        for (int nt = 0; nt < 4; ++nt)
          acc[t][mt][nt] = __builtin_amdgcn_mfma_f32_16x16x32_bf16(
              a, bf[nt], acc[t][mt][nt], 0, 0, 0);
      }
    }
    __syncthreads();
  }

  float local = 0.0f;
#pragma unroll
  for (int mt = 0; mt < MT; ++mt)
#pragma unroll
    for (int nt = 0; nt < 4; ++nt)
#pragma unroll
      for (int reg = 0; reg < 4; ++reg)
        local += fabsf(acc[1][mt][nt][reg] - acc[0][mt][nt][reg]);
  float r = blk_sum256(local, s4);
  if (tid == 0) atomicAdd(&slots[3], r * fscale);
}

__global__ void combine_kernel(const float* __restrict__ slots,
                               float* __restrict__ out) {
  if (threadIdx.x == 0) {
    const float Nn = 1572864.0f;
    const float Nigt = 8388608.0f;
    out[0] = 2.0f * slots[0] / Nn + slots[1] / Nn + slots[2] / Nigt + slots[3];
  }
}

extern "C" void kernel_launch(void* const* d_in, const int* in_sizes, int n_in,
                              void* d_out, int out_size, void* d_ws,
                              size_t ws_size, hipStream_t stream) {
  (void)in_sizes; (void)n_in; (void)out_size;
  const float* igt = (const float*)d_in[0];
  const float* iout = (const float*)d_in[1];
  const float* mask = (const float*)d_in[2];
  const float* w[7];
  const float* b[7];
  for (int i = 0; i < 7; ++i) {
    w[i] = (const float*)d_in[3 + 2 * i];
    b[i] = (const float*)d_in[4 + 2 * i];
  }
  float* slots = (float*)d_ws;
  const unsigned char* zp = (const unsigned char*)d_ws + 64;  // 16B zeros

  unsigned char* wpk = (unsigned char*)((char*)d_ws + 256);
  __hip_bfloat16* w1k = (__hip_bfloat16*)((char*)d_ws + 256 + 1732608);
  // weights end at byte 1,736,960

  const size_t NEED2 = 194674944ULL;
  const int NB = (ws_size >= NEED2) ? 2 : 1;
  const int B3 = 3 * NB;
  const size_t M = (size_t)NB;  // scale factor

  char* base = (char*)d_ws + 1736960;
  // Region A: M*16,777,216 (P1N8 after merged-L2; P2T after L3)
  unsigned char* P1N8 = (unsigned char*)base;
  __hip_bfloat16* P2T = (__hip_bfloat16*)base;
  // Region B (Y1 region): at M*16,777,216, size M*50,331,648
  char* Y1base = base + M * 16777216;
  unsigned char* Y1 = (unsigned char*)Y1base;              // Y1[3] contiguous
  __hip_bfloat16* pgT1 = (__hip_bfloat16*)Y1base;          // after L2 done
  __hip_bfloat16* pcT1 = (__hip_bfloat16*)(Y1base + M * 8388608);
  unsigned char* P2N8 = (unsigned char*)(Y1base + M * 25165824);
  __hip_bfloat16* P2Nb = (__hip_bfloat16*)(Y1base + M * 31457280);
  __hip_bfloat16* P3Nb = (__hip_bfloat16*)Y1base;          // after P1 gram done
  __hip_bfloat16* P3T = (__hip_bfloat16*)(Y1base + M * 6291456);
  // Region C (P1Nb region): at M*67,108,864, size M*25,165,824
  char* Cbase = base + M * 67108864;
  __hip_bfloat16* P1Nb = (__hip_bfloat16*)Cbase;           // 3 streams contig
  unsigned char* T = (unsigned char*)Cbase;                // after transpose P1
  unsigned char* Y5 = (unsigned char*)Cbase;               // after L4 done
  unsigned char* Y6 = (unsigned char*)(Cbase + M * 12582912);
  // End of workspace use: base + M*92,274,688 = 186,286,336 bytes < NEED2.

  const float fs1 = (float)(1.0 / (4194304.0 * 4096.0));
  const float fs2 = (float)(1.0 / (2097152.0 * 16384.0));
  const float fs3 = (float)(1.0 / (1048576.0 * 65536.0));

  init_slots<<<1, 64, 0, stream>>>(slots);
  // Merged prologue: 6x pack_w + pack_w1 + l1 in ONE dispatch.
  pack_all<<<2004, 256, 0, stream>>>(w[0], w[1], w[2], w[3], w[4], w[5], w[6],
                                     igt, iout, mask, wpk, w1k, slots);

  for (int n0 = 0; n0 < 2; n0 += NB) {
    // Stage 1: fused im2col+conv1 for all 3 streams in ONE dispatch.
    conv1f<<<dim3(8, 64, 3 * NB), 256, 0, stream>>>(
        igt, iout, mask, w1k, b[0], Y1, n0, NB, (long)(M * 16777216));
    // ONE merged L2 conv+pool over 3*NB images.
    conv_f8p<<<dim3(8, 128, 3 * NB), 256, 0, stream>>>(
        Y1, wpk + 0, b[1], P1N8, P1Nb, zp, 64, 64, 512, 512);
    // ONE merged transpose: P1Nb[3*NB] -> pgT1|pcT1 (contiguous planes).
    transpose_k<<<dim3(32, 32, 3 * NB * 2), 256, 0, stream>>>(P1Nb, pgT1, 64,
                                                              256, 256);
    // Merged perc+gram over both compare pairs (gt repeats via gN/gtm).
    perc_kernel<<<304, 256, 0, stream>>>(pgT1, pcT1, NB * 1048576,
                                         NB * 524288, slots);
    gram_mfma<128><<<dim3(4, 2, NB * 128), 256, 0, stream>>>(
        pgT1, pcT1, 256, 256, NB * 64, fs1, slots);

    // Stage 2.
    conv_f8<<<dim3(4, 64, B3 * 2), 256, 0, stream>>>(
        P1N8, wpk + 36864, b[2], T, zp, 64, 128, 256, 256);
    conv_f8p<<<dim3(4, 64, B3 * 2), 256, 0, stream>>>(
        T, wpk + 110592, b[3], P2N8, P2Nb, zp, 128, 128, 256, 256);
    transpose_k<<<dim3(16, 16, B3 * 4), 256, 0, stream>>>(P2Nb, P2T, 128, 128,
                                                          128);
    perc_kernel<<<304, 256, 0, stream>>>(P2T, P2T + M * 2097152, NB * 524288,
                                         NB * 262144, slots);
    gram_mfma<128><<<dim3(2, 1, NB * 256), 256, 0, stream>>>(
        P2T, P2T + M * 2097152, 128, 128, NB * 128, fs2, slots);

    // Stage 3.
    conv_f8<<<dim3(2, 32, B3 * 4), 256, 0, stream>>>(
        P2N8, wpk + 258048, b[4], Y5, zp, 128, 256, 128, 128);
    conv_f8<<<dim3(2, 32, B3 * 4), 256, 0, stream>>>(
        Y5, wpk + 552960, b[5], Y6, zp, 256, 256, 128, 128);
    conv_f8p<<<dim3(2, 32, B3 * 4), 256, 0, stream>>>(
        Y6, wpk + 1142784, b[6], (unsigned char*)nullptr, P3Nb, zp, 256, 256,
        128, 128);
    transpose_k<<<dim3(8, 8, B3 * 8), 256, 0, stream>>>(P3Nb, P3T, 256, 64, 64);
    perc_kernel<<<304, 256, 0, stream>>>(P3T, P3T + M * 1048576, NB * 262144,
                                         NB * 131072, slots);
    gram_mfma<64><<<dim3(1, 1, NB * 512), 256, 0, stream>>>(
        P3T, P3T + M * 1048576, 64, 64, NB * 256, fs3, slots);
  }

  combine_kernel<<<1, 64, 0, stream>>>(slots, (float*)d_out);
}

// Round 13
// 685.521 us; speedup vs baseline: 1.3814x; 1.0575x over previous
//
#include <hip/hip_runtime.h>
#include <hip/hip_bf16.h>

// ---------------------------------------------------------------------------
// VGG16 perceptual+style inpainting loss.
// v13 = v12 (725us, best) + conv1f COOPERATIVE im2col: block first builds a
// sel[660] halo tile (66x10 px, 4 bf16/px: 3ch+pad) in LDS -- each halo
// pixel loaded/converted ONCE (bounds/mask/bf16 path identical to pack2 ->
// bit-identical numerics) -- then each thread assembles its 2 im2col rows
// from sel via ds_read_b64. Replaces ~54 redundant scalar global loads +
// cvts per thread (conv1f was 90us @ MfmaUtil 2.7%, VALUBusy 25%).
// All other kernels verbatim v12: conv_f8/conv_f8p (4-row blocks, 3 blk/CU,
// MX-scaled fp8 MFMA scale=1.0, gld16 A-stage, LDS-bounce epilogues),
// merged L2 (z=3NB), merged transposes/perc/gram, pack_all prologue.
// Workspace layout identical.
// ---------------------------------------------------------------------------

typedef __attribute__((ext_vector_type(8))) short bf16x8_t;
typedef __attribute__((ext_vector_type(4))) float f32x4_t;
typedef __attribute__((ext_vector_type(16))) float f32x16_t;
typedef __attribute__((ext_vector_type(8))) int i32x8_t;
typedef __attribute__((ext_vector_type(4))) short s16x4_t;

typedef const __attribute__((address_space(1))) void* gas_t;
typedef __attribute__((address_space(3))) void* las_t;

__device__ __forceinline__ void gld16(const void* g, void* l) {
  __builtin_amdgcn_global_load_lds((gas_t)g, (las_t)l, 16, 0, 0);
}

__device__ __forceinline__ unsigned char f2fp8(float v) {
  return (unsigned char)(__builtin_amdgcn_cvt_pk_fp8_f32(v, v, 0, false) & 0xff);
}

// Read one 32B fragment (logical chunks 2h,2h+1 of a 64B row) from a
// chunk-swizzled LDS tile. Swizzle: physical chunk = logical ^ ((row>>1)&3).
__device__ __forceinline__ i32x8_t ld_frag(const unsigned char* lds, int row,
                                           int h) {
  const int sw = (row >> 1) & 3;
  const unsigned char* base = lds + row * 64;
  uint4 lo = *(const uint4*)(base + (((2 * h) ^ sw) << 4));
  uint4 hi = *(const uint4*)(base + (((2 * h + 1) ^ sw) << 4));
  i32x8_t r;
  r[0] = lo.x; r[1] = lo.y; r[2] = lo.z; r[3] = lo.w;
  r[4] = hi.x; r[5] = hi.y; r[6] = hi.z; r[7] = hi.w;
  return r;
}

// 32 contiguous bytes global -> i32x8 (B fragment direct from L1/L2).
__device__ __forceinline__ i32x8_t ld32g(const unsigned char* p) {
  uint4 lo = *(const uint4*)p;
  uint4 hi = *(const uint4*)(p + 16);
  i32x8_t r;
  r[0] = lo.x; r[1] = lo.y; r[2] = lo.z; r[3] = lo.w;
  r[4] = hi.x; r[5] = hi.y; r[6] = hi.z; r[7] = hi.w;
  return r;
}

__device__ __forceinline__ float blk_sum256(float v, float* s4) {
#pragma unroll
  for (int o = 32; o > 0; o >>= 1) v += __shfl_down(v, o);
  int w = threadIdx.x >> 6;
  if ((threadIdx.x & 63) == 0) s4[w] = v;
  __syncthreads();
  float r = s4[0] + s4[1] + s4[2] + s4[3];
  __syncthreads();
  return r;
}

__global__ void init_slots(float* slots) {
  if (threadIdx.x < 32) slots[threadIdx.x] = 0.0f;  // slots[0..7] + zero-page
}

// ---------------------------------------------------------------------------
// pack_all: merged prologue. Block ranges:
//  [0,1692)    pack_w for layers 0..5 (fp32 OIHW -> fp8 [tap][cout][cin])
//  [1692,1700) pack_w1 (conv1 weights -> bf16 [co][32])
//  [1700,2004) l1_kernel (hole/valid L1 partials -> slots[0..1])
// ---------------------------------------------------------------------------
__global__ __launch_bounds__(256) void pack_all(
    const float* __restrict__ w1, const float* __restrict__ w2,
    const float* __restrict__ w3, const float* __restrict__ w4,
    const float* __restrict__ w5, const float* __restrict__ w6,
    const float* __restrict__ w7, const float* __restrict__ igt,
    const float* __restrict__ iout, const float* __restrict__ mask,
    unsigned char* __restrict__ wpk, __hip_bfloat16* __restrict__ w1k,
    float* __restrict__ slots) {
  __shared__ float s4[4];
  const int b = blockIdx.x;
  if (b < 1692) {
    int start, Cin, Cout;
    long off;
    const float* w;
    if (b < 36)        { start = 0;    Cin = 64;  Cout = 64;  off = 0;       w = w2; }
    else if (b < 108)  { start = 36;   Cin = 64;  Cout = 128; off = 36864;   w = w3; }
    else if (b < 252)  { start = 108;  Cin = 128; Cout = 128; off = 110592;  w = w4; }
    else if (b < 540)  { start = 252;  Cin = 128; Cout = 256; off = 258048;  w = w5; }
    else if (b < 1116) { start = 540;  Cin = 256; Cout = 256; off = 552960;  w = w6; }
    else               { start = 1116; Cin = 256; Cout = 256; off = 1142784; w = w7; }
    unsigned char* wp = wpk + off;
    int i = (b - start) * 256 + threadIdx.x;
    int c4n = Cin >> 2;
    int o = i % 9;
    int rem = i / 9;
    int c4 = rem % c4n;
    int co = rem / c4n;
    int dy = o / 3, dx = o % 3;
    unsigned r = 0;
#pragma unroll
    for (int k = 0; k < 4; ++k) {
      int ci = c4 * 4 + k;
      float v = w[((co * Cin + ci) * 3 + dy) * 3 + dx];
      r |= (unsigned)f2fp8(v) << (8 * k);
    }
    *(unsigned*)(wp + ((long)(o * Cout + co)) * Cin + c4 * 4) = r;
  } else if (b < 1700) {
    int i = (b - 1692) * 256 + threadIdx.x;  // < 2048
    int co = i >> 5, k = i & 31;
    float v = 0.0f;
    if (k < 27) {
      int dy = k / 9, r = k - dy * 9;
      int dx = r / 3, ci = r - dx * 3;
      v = w1[((co * 3 + ci) * 3 + dy) * 3 + dx];
    }
    w1k[i] = __float2bfloat16(v);
  } else {
    int vb = b - 1700;
    float ah = 0.0f, av = 0.0f;
    for (int idx = vb * 256 + threadIdx.x; idx < 1572864; idx += 304 * 256) {
      int pix = idx & 262143;
      int n = idx / 786432;
      float mk = mask[n * 262144 + pix];
      bool m = (mk != 0.0f);
      float d = fabsf(iout[idx] - igt[idx]);
      if (m) av += d; else ah += d;
    }
    float r = blk_sum256(ah, s4);
    if (threadIdx.x == 0) atomicAdd(&slots[0], r);
    r = blk_sum256(av, s4);
    if (threadIdx.x == 0) atomicAdd(&slots[1], r);
  }
}

// ---------------------------------------------------------------------------
// conv1f v2: fused im2col + K=32 bf16 MFMA GEMM -> fp8 NHWC Y1, all 3
// streams in one dispatch (z = s*NB + nl). Phase A: block cooperatively
// builds sel[660] halo tile (4 bf16/px) in LDS -- each halo pixel loaded
// ONCE (pack2-identical values). Phase B: threads assemble im2col rows from
// sel via ds_read_b64. GEMM + LDS-bounce epilogue identical to conv1m.
// ---------------------------------------------------------------------------
__global__ __launch_bounds__(256, 2) void conv1f(
    const float* __restrict__ igt, const float* __restrict__ iout,
    const float* __restrict__ mask, const __hip_bfloat16* __restrict__ wk,
    const float* __restrict__ bias, unsigned char* __restrict__ outb,
    int n0, int NB, long ystride) {
  __shared__ __align__(16) short ApS[512 * 32];
  __shared__ __align__(16) short BwS[64 * 32];
  __shared__ __align__(16) s16x4_t Sel[660];  // halo: [r 10][c 66], 3ch+pad
  const int tid = threadIdx.x;
  const int lane = tid & 63;
  const int wv = tid >> 6;
  const int quad = lane >> 4, l15 = lane & 15;
  const int s = blockIdx.z / NB;
  const int nl = blockIdx.z % NB;
  const int sample = n0 + nl;
  const int x0 = blockIdx.x << 6;
  const int y0 = blockIdx.y << 3;

  // B: 64 entries x 64B = 4 slabs via gld16.
  if (wv < 4) gld16(wk + (lane >> 2) * 32 + (lane & 3) * 8, &BwS[wv << 9]);

  // Phase A: cooperative halo build (each halo pixel once).
  for (int hp = tid; hp < 660; hp += 256) {
    int r = hp / 66, c = hp - r * 66;
    int gy = y0 - 1 + r, gx = x0 - 1 + c;
    bool inb = (gy >= 0 && gy < 512 && gx >= 0 && gx < 512);
    int p = gy * 512 + gx;
    bool useG;
    if (s == 0) useG = true;
    else if (s == 1) useG = false;
    else useG = inb && (mask[sample * 262144 + (inb ? p : 0)] != 0.0f);
    const float* src = useG ? igt : iout;
    s16x4_t v4;
#pragma unroll
    for (int ci = 0; ci < 3; ++ci) {
      float v = inb ? src[sample * 786432 + ci * 262144 + p] : 0.0f;
      __hip_bfloat16 bv = __float2bfloat16(v);
      v4[ci] = *(short*)&bv;
    }
    v4[3] = 0;
    Sel[hp] = v4;
  }
  __syncthreads();

  // Phase B: assemble 2 im2col rows per thread from Sel.
#pragma unroll
  for (int t = 0; t < 2; ++t) {
    int pix = tid + t * 256;  // 0..511
    int r = pix >> 6, c = pix & 63;
    __align__(16) __hip_bfloat16 buf[32];
#pragma unroll
    for (int k = 27; k < 32; ++k) buf[k] = __float2bfloat16(0.0f);
#pragma unroll
    for (int dy = 0; dy < 3; ++dy)
#pragma unroll
      for (int dx = 0; dx < 3; ++dx) {
        s16x4_t v4 = Sel[(r + dy) * 66 + (c + dx)];
        short* bs = (short*)buf;
        bs[dy * 9 + dx * 3 + 0] = v4[0];
        bs[dy * 9 + dx * 3 + 1] = v4[1];
        bs[dy * 9 + dx * 3 + 2] = v4[2];
      }
#pragma unroll
    for (int q = 0; q < 4; ++q)
      *(uint4*)&ApS[pix * 32 + q * 8] = *(const uint4*)&buf[q * 8];
  }
  __syncthreads();

  f32x4_t acc[8][4];
#pragma unroll
  for (int mt = 0; mt < 8; ++mt)
#pragma unroll
    for (int nt = 0; nt < 4; ++nt) acc[mt][nt] = (f32x4_t)0.0f;

  bf16x8_t bf[4];
#pragma unroll
  for (int nt = 0; nt < 4; ++nt)
    bf[nt] = *(const bf16x8_t*)&BwS[(nt * 16 + l15) * 32 + quad * 8];
#pragma unroll
  for (int mt = 0; mt < 8; ++mt) {
    const int rl = 2 * wv + (mt >> 2);
    const int pl = (mt & 3) * 16 + l15;
    const bf16x8_t a = *(const bf16x8_t*)&ApS[(rl * 64 + pl) * 32 + quad * 8];
#pragma unroll
    for (int nt = 0; nt < 4; ++nt)
      acc[mt][nt] = __builtin_amdgcn_mfma_f32_16x16x32_bf16(a, bf[nt],
                                                            acc[mt][nt], 0, 0, 0);
  }

  float bv[4];
#pragma unroll
  for (int nt = 0; nt < 4; ++nt) bv[nt] = bias[nt * 16 + l15];

  __syncthreads();
  unsigned char* O8 = (unsigned char*)ApS;
#pragma unroll
  for (int mt = 0; mt < 8; ++mt) {
    const int ry = 2 * wv + (mt >> 2);
#pragma unroll
    for (int nt = 0; nt < 4; ++nt) {
      const int col = nt * 16 + l15;
#pragma unroll
      for (int reg = 0; reg < 4; ++reg) {
        int px = (mt & 3) * 16 + quad * 4 + reg;
        float v = fmaxf(acc[mt][nt][reg] + bv[nt], 0.0f);
        O8[((ry << 6) + px) * 64 + col] = f2fp8(v);
      }
    }
  }
  __syncthreads();
  unsigned char* out = outb + (long)s * ystride;
#pragma unroll
  for (int j = 0; j < 8; ++j) {
    int L = (j * 256 + tid) << 4;
    int x = (L >> 6) & 63;
    int cq = L & 63;
    *(uint4*)(out + (((long)nl * 512 + y0 + j) * 512 + x0 + x) * 64 + cq) =
        *(const uint4*)&O8[L];
  }
}

// ---------------------------------------------------------------------------
// conv_f8 v6: 4-row block, wave = (row-pair pr, co-half ch). acc 64 regs,
// A-tile 25.6KB, 3 blocks/CU. MX MFMA K=64 per tap. (r5/r8/r11-proven)
// ---------------------------------------------------------------------------
__global__ __launch_bounds__(256, 3) void conv_f8(
    const unsigned char* __restrict__ act, const unsigned char* __restrict__ wp,
    const float* __restrict__ bias, unsigned char* __restrict__ out,
    const unsigned char* __restrict__ zp, int Cin, int Cout, int H, int W) {
  __shared__ __align__(16) unsigned char ApS[400 * 64];
  const int tid = threadIdx.x;
  const int lane = tid & 63;
  const int wv = tid >> 6;
  const int l31 = lane & 31;
  const int h = lane >> 5;
  const int pr = wv & 1;   // row pair: rows 2pr, 2pr+1
  const int ch = wv >> 1;  // co half: ch*32
  const int coB = Cout >> 6;
  const int n = blockIdx.z / coB;
  const int co0 = (blockIdx.z % coB) << 6;
  const int x0 = blockIdx.x << 6;
  const int y0 = blockIdx.y << 2;
  const int spos = lane >> 2;
  const int sc = lane & 3;

  f32x16_t acc[2][2];
#pragma unroll
  for (int dr = 0; dr < 2; ++dr)
#pragma unroll
    for (int mh = 0; mh < 2; ++mh) acc[dr][mh] = (f32x16_t)0.0f;

  for (int cb = 0; cb < Cin; cb += 64) {
    if (cb) __syncthreads();  // guard ApS reuse
    for (int u = wv; u < 25; u += 4) {
      int pos = (u << 4) + spos;
      int q = sc ^ ((pos >> 1) & 3);  // inverse swizzle on the SOURCE
      int r = pos / 66, c = pos - r * 66;
      int gy = y0 - 1 + r, gx = x0 - 1 + c;
      const unsigned char* src = zp;
      if (pos < 396 && gy >= 0 && gy < H && gx >= 0 && gx < W)
        src = act + ((long)((long)n * H + gy) * W + gx) * Cin + cb + (q << 4);
      gld16(src, &ApS[u << 10]);
    }
    __syncthreads();

    const unsigned char* wl =
        wp + ((long)(co0 + (ch << 5) + l31)) * Cin + cb + (h << 5);
#pragma unroll
    for (int dx = 0; dx < 3; ++dx) {
      i32x8_t Af[2][4];
#pragma unroll
      for (int mh = 0; mh < 2; ++mh)
#pragma unroll
        for (int ri = 0; ri < 4; ++ri)
          Af[mh][ri] =
              ld_frag(ApS, (2 * pr + ri) * 66 + mh * 32 + l31 + dx, h);
#pragma unroll
      for (int dy = 0; dy < 3; ++dy) {
        const int o = dy * 3 + dx;
        i32x8_t Bf = ld32g(wl + (long)o * Cout * Cin);
#pragma unroll
        for (int dr = 0; dr < 2; ++dr)
#pragma unroll
          for (int mh = 0; mh < 2; ++mh)
            acc[dr][mh] = __builtin_amdgcn_mfma_scale_f32_32x32x64_f8f6f4(
                Af[mh][dr + dy], Bf, acc[dr][mh], 0, 0, 0,
                0x7F7F7F7F, 0, 0x7F7F7F7F);
      }
    }
  }

  const float bv = bias[co0 + (ch << 5) + l31];

  // LDS bounce: ApS reused as fp8 tile [ry 4][x 64][co 64] = 16KB.
  __syncthreads();
#pragma unroll
  for (int dr = 0; dr < 2; ++dr) {
    const int ry = 2 * pr + dr;
#pragma unroll
    for (int mh = 0; mh < 2; ++mh) {
#pragma unroll
      for (int reg = 0; reg < 16; ++reg) {
        int rowM = (reg & 3) + 8 * (reg >> 2) + 4 * h;
        int x = mh * 32 + rowM;
        float v = fmaxf(acc[dr][mh][reg] + bv, 0.0f);
        ApS[((ry << 6) + x) * 64 + (ch << 5) + l31] = f2fp8(v);
      }
    }
  }
  __syncthreads();
#pragma unroll
  for (int j = 0; j < 4; ++j) {
    int L = (j * 256 + tid) << 4;
    int ry = L >> 12;
    int x = (L >> 6) & 63;
    int cq = L & 63;
    *(uint4*)(out + (((long)n * H + y0 + ry) * W + x0 + x) * Cout + co0 + cq) =
        *(const uint4*)&ApS[L];
  }
}

// conv_f8p v6: conv_f8 + fused 2x2 maxpool; wide dual-store via LDS bounce.
// outF may be nullptr (fp8 output unused, e.g. last layer).
__global__ __launch_bounds__(256, 3) void conv_f8p(
    const unsigned char* __restrict__ act, const unsigned char* __restrict__ wp,
    const float* __restrict__ bias, unsigned char* __restrict__ outF,
    __hip_bfloat16* __restrict__ outB, const unsigned char* __restrict__ zp,
    int Cin, int Cout, int H, int W) {
  __shared__ __align__(16) unsigned char ApS[400 * 64];
  const int tid = threadIdx.x;
  const int lane = tid & 63;
  const int wv = tid >> 6;
  const int l31 = lane & 31;
  const int h = lane >> 5;
  const int pr = wv & 1;
  const int ch = wv >> 1;
  const int coB = Cout >> 6;
  const int n = blockIdx.z / coB;
  const int co0 = (blockIdx.z % coB) << 6;
  const int x0g = blockIdx.x << 6;
  const int y0 = blockIdx.y << 2;
  const int spos = lane >> 2;
  const int sc = lane & 3;

  f32x16_t acc[2][2];
#pragma unroll
  for (int dr = 0; dr < 2; ++dr)
#pragma unroll
    for (int mh = 0; mh < 2; ++mh) acc[dr][mh] = (f32x16_t)0.0f;

  for (int cb = 0; cb < Cin; cb += 64) {
    if (cb) __syncthreads();
    for (int u = wv; u < 25; u += 4) {
      int pos = (u << 4) + spos;
      int q = sc ^ ((pos >> 1) & 3);
      int r = pos / 66, c = pos - r * 66;
      int gy = y0 - 1 + r, gx = x0g - 1 + c;
      const unsigned char* src = zp;
      if (pos < 396 && gy >= 0 && gy < H && gx >= 0 && gx < W)
        src = act + ((long)((long)n * H + gy) * W + gx) * Cin + cb + (q << 4);
      gld16(src, &ApS[u << 10]);
    }
    __syncthreads();

    const unsigned char* wl =
        wp + ((long)(co0 + (ch << 5) + l31)) * Cin + cb + (h << 5);
#pragma unroll
    for (int dx = 0; dx < 3; ++dx) {
      i32x8_t Af[2][4];
#pragma unroll
      for (int mh = 0; mh < 2; ++mh)
#pragma unroll
        for (int ri = 0; ri < 4; ++ri)
          Af[mh][ri] =
              ld_frag(ApS, (2 * pr + ri) * 66 + mh * 32 + l31 + dx, h);
#pragma unroll
      for (int dy = 0; dy < 3; ++dy) {
        const int o = dy * 3 + dx;
        i32x8_t Bf = ld32g(wl + (long)o * Cout * Cin);
#pragma unroll
        for (int dr = 0; dr < 2; ++dr)
#pragma unroll
          for (int mh = 0; mh < 2; ++mh)
            acc[dr][mh] = __builtin_amdgcn_mfma_scale_f32_32x32x64_f8f6f4(
                Af[mh][dr + dy], Bf, acc[dr][mh], 0, 0, 0,
                0x7F7F7F7F, 0, 0x7F7F7F7F);
      }
    }
  }

  const int Ho = H >> 1, Wo = W >> 1;
  const int ho0 = blockIdx.y << 1;
  const int wo0 = blockIdx.x << 5;
  const float bv = bias[co0 + (ch << 5) + l31];

  // LDS bounce: fp8 tile [ho 2][wo 32][co 64] = 4KB, bf16 same layout 8KB.
  __syncthreads();
  unsigned char* F8 = ApS;
  __hip_bfloat16* BB = (__hip_bfloat16*)(ApS + 4096);
#pragma unroll
  for (int mh = 0; mh < 2; ++mh) {
#pragma unroll
    for (int p8 = 0; p8 < 8; ++p8) {
      const int reg = 2 * p8;  // (reg,reg+1) = x-adjacent pair
      float m0 = fmaxf(fmaxf(acc[0][mh][reg], acc[0][mh][reg + 1]),
                       fmaxf(acc[1][mh][reg], acc[1][mh][reg + 1]));
      float v = fmaxf(m0 + bv, 0.0f);
      int rowM = (reg & 3) + 8 * (reg >> 2) + 4 * h;
      int wo = mh * 16 + (rowM >> 1);  // 0..31
      int off = ((pr * 32 + wo) << 6) + (ch << 5) + l31;
      if (outF) F8[off] = f2fp8(v);
      BB[off] = __float2bfloat16(v);
    }
  }
  __syncthreads();
  if (outF) {
    int L = tid << 4;
    int hl = L >> 11;
    int wo = (L >> 6) & 31;
    int cq = L & 63;
    *(uint4*)(outF + (((long)n * Ho + ho0 + hl) * Wo + wo0 + wo) * Cout + co0 +
              cq) = *(const uint4*)&F8[L];
  }
#pragma unroll
  for (int j = 0; j < 2; ++j) {
    int S = (j * 256 + tid) << 3;  // short index
    int hl = S >> 11;
    int wo = (S >> 6) & 31;
    int cq = S & 63;
    *(uint4*)(outB + (((long)n * Ho + ho0 + hl) * Wo + wo0 + wo) * Cout + co0 +
              cq) = *(const uint4*)&BB[S];
  }
}

// NHWC [j][Ho][Wo][C] -> col-major planar [(j*C+c)][Wo][Ho]. (r10-proven)
__global__ __launch_bounds__(256) void transpose_k(
    const __hip_bfloat16* __restrict__ in, __hip_bfloat16* __restrict__ out,
    int C, int Ho, int Wo) {
  const int cl = threadIdx.x & 31;
  const int wl = threadIdx.x >> 5;
  const int cg = C >> 5;
  const int j = blockIdx.z / cg;
  const int c = (blockIdx.z % cg) * 32 + cl;
  const int wo = blockIdx.x * 8 + wl;
  const int ho0 = blockIdx.y * 8;
  __align__(16) __hip_bfloat16 res[8];
#pragma unroll
  for (int i = 0; i < 8; ++i)
    res[i] = in[(((long)j * Ho + ho0 + i) * Wo + wo) * C + c];
  *(uint4*)&out[((long)(j * C + c) * Wo + wo) * Ho + ho0] =
      *(const uint4*)res;
}

// l_perc partial: sum |cur - gt| over 8*M8 bf16 elements -> slots[2].
// gt repeats every gN 16B-groups (merged multi-stream compare).
__global__ __launch_bounds__(256) void perc_kernel(
    const __hip_bfloat16* __restrict__ gt, const __hip_bfloat16* __restrict__ cur,
    int M8, int gN, float* __restrict__ slots) {
  __shared__ float s4[4];
  const uint4* g4 = (const uint4*)gt;
  const uint4* c4 = (const uint4*)cur;
  float acc = 0.0f;
  for (int i = blockIdx.x * 256 + threadIdx.x; i < M8; i += gridDim.x * 256) {
    int ig = (i >= gN) ? i - gN : i;
    uint4 g = g4[ig], c = c4[i];
    const unsigned* gu = (const unsigned*)&g;
    const unsigned* cu = (const unsigned*)&c;
#pragma unroll
    for (int k = 0; k < 4; ++k) {
      float g0 = __uint_as_float(gu[k] << 16);
      float g1 = __uint_as_float(gu[k] & 0xffff0000u);
      float c0 = __uint_as_float(cu[k] << 16);
      float c1 = __uint_as_float(cu[k] & 0xffff0000u);
      acc += fabsf(c0 - g0) + fabsf(c1 - g1);
    }
  }
  float r = blk_sum256(acc, s4);
  if (threadIdx.x == 0) atomicAdd(&slots[2], r);
}

// Style partial via bf16 MFMA (r5-proven). Inputs col-major planar bf16.
// gt planes repeat every gtm z-planes (merged multi-stream compare).
template <int BM>
__global__ __launch_bounds__(256) void gram_mfma(
    const __hip_bfloat16* __restrict__ gt_p,
    const __hip_bfloat16* __restrict__ cur_p, int Wp, int Hp, int gtm,
    float fscale, float* __restrict__ slots) {
  constexpr int COLS = BM + 64;
  constexpr int WR = BM / 4;
  constexpr int MT = WR / 16;
  __shared__ __align__(16) short S[2 * COLS * 40];
  __shared__ float s4[4];
  const int tid = threadIdx.x;
  const int lane = tid & 63;
  const int wvi = tid >> 6;
  const int quad = lane >> 4, l15 = lane & 15;
  const int vt = blockIdx.x * 64;
  const int wt = blockIdx.y * BM;
  const long plane = (long)blockIdx.z * Wp * Hp;
  const long plane_g = (long)(blockIdx.z % gtm) * Wp * Hp;
  const __hip_bfloat16* bases[2] = {gt_p + plane_g, cur_p + plane};

  f32x4_t acc[2][MT][4];
#pragma unroll
  for (int t = 0; t < 2; ++t)
#pragma unroll
    for (int mt = 0; mt < MT; ++mt)
#pragma unroll
      for (int nt = 0; nt < 4; ++nt) acc[t][mt][nt] = (f32x4_t)0.0f;

  const int nchunk = 2 * COLS * 4;
  for (int h0 = 0; h0 < Hp; h0 += 32) {
    for (int e = tid; e < nchunk; e += 256) {
      int chunk = e & 3;
      int colt = e >> 2;
      int t = colt / COLS;
      int col = colt - t * COLS;
      int sc = (col < BM) ? (wt + col) : (vt + col - BM);
      uint4 v = *(const uint4*)(bases[t] + (long)sc * Hp + h0 + chunk * 8);
      *(uint4*)&S[(t * COLS + col) * 40 + chunk * 8] = v;
    }
    __syncthreads();
#pragma unroll
    for (int t = 0; t < 2; ++t) {
      bf16x8_t bf[4];
#pragma unroll
      for (int nt = 0; nt < 4; ++nt)
        bf[nt] = *(const bf16x8_t*)&S[(t * COLS + BM + nt * 16 + l15) * 40 +
                                      quad * 8];
#pragma unroll
      for (int mt = 0; mt < MT; ++mt) {
        bf16x8_t a = *(const bf16x8_t*)&S[(t * COLS + wvi * WR + mt * 16 + l15) *
                                              40 + quad * 8];
#pragma unroll
        for (int nt = 0; nt < 4; ++nt)
          acc[t][mt][nt] = __builtin_amdgcn_mfma_f32_16x16x32_bf16(
              a, bf[nt], acc[t][mt][nt], 0, 0, 0);
      }
    }
    __syncthreads();
  }

  float local = 0.0f;
#pragma unroll
  for (int mt = 0; mt < MT; ++mt)
#pragma unroll
    for (int nt = 0; nt < 4; ++nt)
#pragma unroll
      for (int reg = 0; reg < 4; ++reg)
        local += fabsf(acc[1][mt][nt][reg] - acc[0][mt][nt][reg]);
  float r = blk_sum256(local, s4);
  if (tid == 0) atomicAdd(&slots[3], r * fscale);
}

__global__ void combine_kernel(const float* __restrict__ slots,
                               float* __restrict__ out) {
  if (threadIdx.x == 0) {
    const float Nn = 1572864.0f;
    const float Nigt = 8388608.0f;
    out[0] = 2.0f * slots[0] / Nn + slots[1] / Nn + slots[2] / Nigt + slots[3];
  }
}

extern "C" void kernel_launch(void* const* d_in, const int* in_sizes, int n_in,
                              void* d_out, int out_size, void* d_ws,
                              size_t ws_size, hipStream_t stream) {
  (void)in_sizes; (void)n_in; (void)out_size;
  const float* igt = (const float*)d_in[0];
  const float* iout = (const float*)d_in[1];
  const float* mask = (const float*)d_in[2];
  const float* w[7];
  const float* b[7];
  for (int i = 0; i < 7; ++i) {
    w[i] = (const float*)d_in[3 + 2 * i];
    b[i] = (const float*)d_in[4 + 2 * i];
  }
  float* slots = (float*)d_ws;
  const unsigned char* zp = (const unsigned char*)d_ws + 64;  // 16B zeros

  unsigned char* wpk = (unsigned char*)((char*)d_ws + 256);
  __hip_bfloat16* w1k = (__hip_bfloat16*)((char*)d_ws + 256 + 1732608);
  // weights end at byte 1,736,960

  const size_t NEED2 = 194674944ULL;
  const int NB = (ws_size >= NEED2) ? 2 : 1;
  const int B3 = 3 * NB;
  const size_t M = (size_t)NB;  // scale factor

  char* base = (char*)d_ws + 1736960;
  // Region A: M*16,777,216 (P1N8 after merged-L2; P2T after L3)
  unsigned char* P1N8 = (unsigned char*)base;
  __hip_bfloat16* P2T = (__hip_bfloat16*)base;
  // Region B (Y1 region): at M*16,777,216, size M*50,331,648
  char* Y1base = base + M * 16777216;
  unsigned char* Y1 = (unsigned char*)Y1base;              // Y1[3] contiguous
  __hip_bfloat16* pgT1 = (__hip_bfloat16*)Y1base;          // after L2 done
  __hip_bfloat16* pcT1 = (__hip_bfloat16*)(Y1base + M * 8388608);
  unsigned char* P2N8 = (unsigned char*)(Y1base + M * 25165824);
  __hip_bfloat16* P2Nb = (__hip_bfloat16*)(Y1base + M * 31457280);
  __hip_bfloat16* P3Nb = (__hip_bfloat16*)Y1base;          // after P1 gram done
  __hip_bfloat16* P3T = (__hip_bfloat16*)(Y1base + M * 6291456);
  // Region C (P1Nb region): at M*67,108,864, size M*25,165,824
  char* Cbase = base + M * 67108864;
  __hip_bfloat16* P1Nb = (__hip_bfloat16*)Cbase;           // 3 streams contig
  unsigned char* T = (unsigned char*)Cbase;                // after transpose P1
  unsigned char* Y5 = (unsigned char*)Cbase;               // after L4 done
  unsigned char* Y6 = (unsigned char*)(Cbase + M * 12582912);
  // End of workspace use: base + M*92,274,688 = 186,286,336 bytes < NEED2.

  const float fs1 = (float)(1.0 / (4194304.0 * 4096.0));
  const float fs2 = (float)(1.0 / (2097152.0 * 16384.0));
  const float fs3 = (float)(1.0 / (1048576.0 * 65536.0));

  init_slots<<<1, 64, 0, stream>>>(slots);
  // Merged prologue: 6x pack_w + pack_w1 + l1 in ONE dispatch.
  pack_all<<<2004, 256, 0, stream>>>(w[0], w[1], w[2], w[3], w[4], w[5], w[6],
                                     igt, iout, mask, wpk, w1k, slots);

  for (int n0 = 0; n0 < 2; n0 += NB) {
    // Stage 1: fused im2col+conv1 for all 3 streams in ONE dispatch.
    conv1f<<<dim3(8, 64, 3 * NB), 256, 0, stream>>>(
        igt, iout, mask, w1k, b[0], Y1, n0, NB, (long)(M * 16777216));
    // ONE merged L2 conv+pool over 3*NB images.
    conv_f8p<<<dim3(8, 128, 3 * NB), 256, 0, stream>>>(
        Y1, wpk + 0, b[1], P1N8, P1Nb, zp, 64, 64, 512, 512);
    // ONE merged transpose: P1Nb[3*NB] -> pgT1|pcT1 (contiguous planes).
    transpose_k<<<dim3(32, 32, 3 * NB * 2), 256, 0, stream>>>(P1Nb, pgT1, 64,
                                                              256, 256);
    // Merged perc+gram over both compare pairs (gt repeats via gN/gtm).
    perc_kernel<<<304, 256, 0, stream>>>(pgT1, pcT1, NB * 1048576,
                                         NB * 524288, slots);
    gram_mfma<128><<<dim3(4, 2, NB * 128), 256, 0, stream>>>(
        pgT1, pcT1, 256, 256, NB * 64, fs1, slots);

    // Stage 2.
    conv_f8<<<dim3(4, 64, B3 * 2), 256, 0, stream>>>(
        P1N8, wpk + 36864, b[2], T, zp, 64, 128, 256, 256);
    conv_f8p<<<dim3(4, 64, B3 * 2), 256, 0, stream>>>(
        T, wpk + 110592, b[3], P2N8, P2Nb, zp, 128, 128, 256, 256);
    transpose_k<<<dim3(16, 16, B3 * 4), 256, 0, stream>>>(P2Nb, P2T, 128, 128,
                                                          128);
    perc_kernel<<<304, 256, 0, stream>>>(P2T, P2T + M * 2097152, NB * 524288,
                                         NB * 262144, slots);
    gram_mfma<128><<<dim3(2, 1, NB * 256), 256, 0, stream>>>(
        P2T, P2T + M * 2097152, 128, 128, NB * 128, fs2, slots);

    // Stage 3.
    conv_f8<<<dim3(2, 32, B3 * 4), 256, 0, stream>>>(
        P2N8, wpk + 258048, b[4], Y5, zp, 128, 256, 128, 128);
    conv_f8<<<dim3(2, 32, B3 * 4), 256, 0, stream>>>(
        Y5, wpk + 552960, b[5], Y6, zp, 256, 256, 128, 128);
    conv_f8p<<<dim3(2, 32, B3 * 4), 256, 0, stream>>>(
        Y6, wpk + 1142784, b[6], (unsigned char*)nullptr, P3Nb, zp, 256, 256,
        128, 128);
    transpose_k<<<dim3(8, 8, B3 * 8), 256, 0, stream>>>(P3Nb, P3T, 256, 64, 64);
    perc_kernel<<<304, 256, 0, stream>>>(P3T, P3T + M * 1048576, NB * 262144,
                                         NB * 131072, slots);
    gram_mfma<64><<<dim3(1, 1, NB * 512), 256, 0, stream>>>(
        P3T, P3T + M * 1048576, 64, 64, NB * 256, fs3, slots);
  }

  combine_kernel<<<1, 64, 0, stream>>>(slots, (float*)d_out);
}